// Round 12
// baseline (301.059 us; speedup 1.0000x reference)
//
#include <hip/hip_runtime.h>
#include <math.h>

#define G 2
#define BB 2
#define L 1024
#define DM 256
#define DI 512
#define DS 16
#define DR 16
#define CH 64
#define CL 16              // L / CH
#define RTOT (G*BB*L)      // 4096 rows per layer-step
#define SKX 8              // x_proj split-K factor
#define YSTR 514           // Ys LDS row stride (shorts); 257 words == 1 mod 32

#define NWIN  (4 * 2 * DI * DM)   // in_proj elements (4 layers)
#define NWOUT (4 * DM * DI)       // out_proj elements

typedef short bh8 __attribute__((ext_vector_type(8)));
typedef float f4x __attribute__((ext_vector_type(4)));

__device__ __forceinline__ float silu_f(float x) { return x / (1.f + __expf(-x)); }

__device__ __forceinline__ unsigned short f2bf(float f) {
    unsigned u = __float_as_uint(f);
    unsigned r = u + 0x7FFFu + ((u >> 16) & 1u);
    return (unsigned short)(r >> 16);
}
__device__ __forceinline__ float bf2f(unsigned short s) {
    return __uint_as_float(((unsigned)s) << 16);
}

// ---------------------------------------------------------------------------
// One-time weight pre-conversion (both weight arrays in ONE dispatch):
// fp32 -> (bf16 hi, bf16 lo) pairs.
// ---------------------------------------------------------------------------
__global__ __launch_bounds__(256) void cvtW2(
    const float* __restrict__ Wa, short* __restrict__ Wah, short* __restrict__ Wal, int n4a,
    const float* __restrict__ Wb, short* __restrict__ Wbh, short* __restrict__ Wbl, int n4b)
{
    int i = blockIdx.x * 256 + threadIdx.x;
    const float* W; short *Wh, *Wl;
    if (i < n4a) { W = Wa; Wh = Wah; Wl = Wal; }
    else if (i < n4a + n4b) { i -= n4a; W = Wb; Wh = Wbh; Wl = Wbl; }
    else return;
    float4 v = *(const float4*)&W[(size_t)i * 4];
    short4 h, l;
    unsigned short s;
    s = f2bf(v.x); h.x = (short)s; l.x = (short)f2bf(v.x - bf2f(s));
    s = f2bf(v.y); h.y = (short)s; l.y = (short)f2bf(v.y - bf2f(s));
    s = f2bf(v.z); h.z = (short)s; l.z = (short)f2bf(v.z - bf2f(s));
    s = f2bf(v.w); h.w = (short)s; l.w = (short)f2bf(v.w - bf2f(s));
    *(short4*)&Wh[(size_t)i * 4] = h;
    *(short4*)&Wl[(size_t)i * 4] = l;
}

// ---------------------------------------------------------------------------
// in_proj MFMA GEMM (3xbf16). BM=128, N=1024, K=256.
// AMAP 1: A = x (fp32) with g-dependent time reversal (step 0).
// AMAP 0: A = Pout as pre-split bf16 hi/lo (step 1) - cvt-free staging.
// B always pre-converted (Wh/Wl). lay = (row0>>11)*2 + step.
// ---------------------------------------------------------------------------
template<int AMAP>
__global__ __launch_bounds__(256) void mfma_inproj(
    const float* __restrict__ Ax,
    const short* __restrict__ Ah, const short* __restrict__ Al,
    const short* __restrict__ Wh, const short* __restrict__ Wl,
    int step, float* __restrict__ C)
{
    constexpr int BM = 128, Ktot = DM, Nout = 2 * DI, ldc = 1024;
    __shared__ short As_hi[BM * 40];
    __shared__ short As_lo[BM * 40];
    __shared__ short Bs_hi[64 * 40];
    __shared__ short Bs_lo[64 * 40];

    const int row0 = blockIdx.y * BM;
    const int col0 = blockIdx.x * 64;
    const int g    = row0 >> 11;
    const int lay  = g * 2 + step;
    const short* Whg = Wh + (size_t)lay * Nout * Ktot;
    const short* Wlg = Wl + (size_t)lay * Nout * Ktot;
    const int t    = threadIdx.x;
    const int lane = t & 63, wv = t >> 6;
    const int m = lane & 15, quad = lane >> 4;
    const int wr = wv >> 1, wc = wv & 1;
    const int NT = Ktot / 32;     // 8

    float4 pa[4];
    short4 pah[4], pal[4], pbh[2], pbl[2];
    auto loadT = [&](int kt) {
        const int kb = kt * 32;
        #pragma unroll
        for (int i = 0; i < 4; i++) {
            int id = t + 256 * i;
            int row = id >> 3, kq = id & 7;
            if (AMAP == 1) {
                int gr = row0 + row;
                int gg = gr >> 11, b = (gr >> 10) & 1, l = gr & 1023;
                int sl = gg ? (1023 - l) : l;
                pa[i] = *(const float4*)&Ax[(size_t)(b * 1024 + sl) * Ktot + kb + kq * 4];
            } else {
                size_t o = (size_t)(row0 + row) * Ktot + kb + kq * 4;
                pah[i] = *(const short4*)&Ah[o];
                pal[i] = *(const short4*)&Al[o];
            }
        }
        #pragma unroll
        for (int i = 0; i < 2; i++) {
            int id = t + 256 * i;
            int row = id >> 3, kq = id & 7;
            size_t o = (size_t)(col0 + row) * Ktot + kb + kq * 4;
            pbh[i] = *(const short4*)&Whg[o];
            pbl[i] = *(const short4*)&Wlg[o];
        }
    };

    f4x acc[4][2] = {};
    loadT(0);

    for (int kt = 0; kt < NT; kt++) {
        #pragma unroll
        for (int i = 0; i < 4; i++) {
            int id = t + 256 * i;
            int row = id >> 3, kq = id & 7;
            if (AMAP == 1) {
                float4 v = pa[i];
                short4 h, l;
                unsigned short s;
                s = f2bf(v.x); h.x = (short)s; l.x = (short)f2bf(v.x - bf2f(s));
                s = f2bf(v.y); h.y = (short)s; l.y = (short)f2bf(v.y - bf2f(s));
                s = f2bf(v.z); h.z = (short)s; l.z = (short)f2bf(v.z - bf2f(s));
                s = f2bf(v.w); h.w = (short)s; l.w = (short)f2bf(v.w - bf2f(s));
                *(short4*)&As_hi[row * 40 + kq * 4] = h;
                *(short4*)&As_lo[row * 40 + kq * 4] = l;
            } else {
                *(short4*)&As_hi[row * 40 + kq * 4] = pah[i];
                *(short4*)&As_lo[row * 40 + kq * 4] = pal[i];
            }
        }
        #pragma unroll
        for (int i = 0; i < 2; i++) {
            int id = t + 256 * i;
            int row = id >> 3, kq = id & 7;
            *(short4*)&Bs_hi[row * 40 + kq * 4] = pbh[i];
            *(short4*)&Bs_lo[row * 40 + kq * 4] = pbl[i];
        }
        __syncthreads();
        if (kt + 1 < NT) loadT(kt + 1);

        bh8 ah[4], al[4], bh[2], bl[2];
        #pragma unroll
        for (int p = 0; p < 4; p++) {
            int r = wr * 64 + p * 16 + m;
            ah[p] = *(bh8*)&As_hi[r * 40 + quad * 8];
            al[p] = *(bh8*)&As_lo[r * 40 + quad * 8];
        }
        #pragma unroll
        for (int q = 0; q < 2; q++) {
            int r = wc * 32 + q * 16 + m;
            bh[q] = *(bh8*)&Bs_hi[r * 40 + quad * 8];
            bl[q] = *(bh8*)&Bs_lo[r * 40 + quad * 8];
        }
        #pragma unroll
        for (int p = 0; p < 4; p++)
            #pragma unroll
            for (int q = 0; q < 2; q++) {
                acc[p][q] = __builtin_amdgcn_mfma_f32_16x16x32_bf16(ah[p], bh[q], acc[p][q], 0, 0, 0);
                acc[p][q] = __builtin_amdgcn_mfma_f32_16x16x32_bf16(ah[p], bl[q], acc[p][q], 0, 0, 0);
                acc[p][q] = __builtin_amdgcn_mfma_f32_16x16x32_bf16(al[p], bh[q], acc[p][q], 0, 0, 0);
            }
        __syncthreads();
    }

    #pragma unroll
    for (int p = 0; p < 4; p++)
        #pragma unroll
        for (int q = 0; q < 2; q++) {
            int gcol = col0 + wc * 32 + q * 16 + m;
            #pragma unroll
            for (int r = 0; r < 4; r++) {
                int grow = row0 + wr * 64 + p * 16 + quad * 4 + r;
                C[(size_t)grow * ldc + gcol] = acc[p][q][r];
            }
        }
}

// ---------------------------------------------------------------------------
// x_proj GEMM (fp32) with the depthwise conv+silu FUSED into the A-staging.
// A[r][ch] = silu(conv(XZ[.., ch])) computed on the fly; side-writes XCb.
// ---------------------------------------------------------------------------
template<int SPLITK>
__global__ __launch_bounds__(256) void gemm_xproj(
    const float* __restrict__ XZ, const float* __restrict__ cw,
    const float* __restrict__ cb, float* __restrict__ XCb,
    const float* __restrict__ W, int step,
    float* __restrict__ C, size_t partStride)
{
    constexpr int Nout = 48, Ktot = DI;
    __shared__ float As[16][68];
    __shared__ float Bs[16][68];

    const int row0 = blockIdx.y * 64;
    const int g    = row0 >> 11;
    const int lay  = g * 2 + step;
    const float* Wg = W + (size_t)lay * Nout * Ktot;
    const int t  = threadIdx.x;
    const int tx = t & 15, ty = t >> 4;
    const int Kc    = Ktot / SPLITK;
    const int kbase = blockIdx.z * Kc;
    const int NT    = Kc / 16;

    const int sr = t >> 2;
    const int sk = (t & 3) * 4;
    const int gr = row0 + sr;
    const int l  = gr & 1023;
    const bool bok = (sr < Nout);

    float4 pa, pb;
    auto loadT = [&](int kt) {
        const int ch = kbase + kt * 16 + sk;
        const float* wb = cw + ((size_t)lay * 512 + ch) * 4;
        float4 w0 = *(const float4*)&wb[0];
        float4 w1 = *(const float4*)&wb[4];
        float4 w2 = *(const float4*)&wb[8];
        float4 w3 = *(const float4*)&wb[12];
        float4 acc = *(const float4*)&cb[(size_t)lay * 512 + ch];
        #pragma unroll
        for (int k = 0; k < 4; k++) {
            if (l - 3 + k < 0) continue;
            float4 xv = *(const float4*)&XZ[(size_t)(gr - 3 + k) * 1024 + ch];
            acc.x += (&w0.x)[k] * xv.x; acc.y += (&w1.x)[k] * xv.y;
            acc.z += (&w2.x)[k] * xv.z; acc.w += (&w3.x)[k] * xv.w;
        }
        acc.x = silu_f(acc.x); acc.y = silu_f(acc.y);
        acc.z = silu_f(acc.z); acc.w = silu_f(acc.w);
        pa = acc;
        *(float4*)&XCb[(size_t)gr * 512 + ch] = acc;     // side product
        pb = bok ? *(const float4*)&Wg[(size_t)sr * Ktot + kbase + kt * 16 + sk]
                 : make_float4(0.f, 0.f, 0.f, 0.f);
    };

    float acc[4][4] = {};
    loadT(0);

    for (int kt = 0; kt < NT; kt++) {
        As[sk + 0][sr] = pa.x; As[sk + 1][sr] = pa.y;
        As[sk + 2][sr] = pa.z; As[sk + 3][sr] = pa.w;
        Bs[sk + 0][sr] = pb.x; Bs[sk + 1][sr] = pb.y;
        Bs[sk + 2][sr] = pb.z; Bs[sk + 3][sr] = pb.w;
        __syncthreads();
        if (kt + 1 < NT) loadT(kt + 1);
        #pragma unroll
        for (int kk = 0; kk < 16; kk++) {
            float4 a = *(const float4*)&As[kk][ty * 4];
            float4 b = *(const float4*)&Bs[kk][tx * 4];
            float av[4] = {a.x, a.y, a.z, a.w};
            float bv[4] = {b.x, b.y, b.z, b.w};
            #pragma unroll
            for (int i = 0; i < 4; i++)
                #pragma unroll
                for (int j = 0; j < 4; j++) acc[i][j] += av[i] * bv[j];
        }
        __syncthreads();
    }

    float* Cz = C + (size_t)blockIdx.z * partStride;
    const int col = tx * 4;
    if (col < Nout) {
        #pragma unroll
        for (int i = 0; i < 4; i++) {
            int r = row0 + ty * 4 + i;
            *(float4*)&Cz[(size_t)r * 48 + col] =
                make_float4(acc[i][0], acc[i][1], acc[i][2], acc[i][3]);
        }
    }
}

// ---------------------------------------------------------------------------
// Stage dbl chunk (summing the SKX x_proj slabs) into LDS.
// ---------------------------------------------------------------------------
__device__ __forceinline__ void stage_dbl(
    float dbl[CL][48], const float* __restrict__ Pdbl, int r0, int tid)
{
    for (int id = tid; id < CL * 48; id += 512) {
        int rr = id / 48, cc = id - rr * 48;
        size_t o = (size_t)(r0 + rr) * 48 + cc;
        float v = 0.f;
        #pragma unroll
        for (int s = 0; s < SKX; s++) v += Pdbl[(size_t)s * (RTOT * 48) + o];
        dbl[rr][cc] = v;
    }
}

// ---------------------------------------------------------------------------
// Scan phase A: per (gb,chunk,d) -> prod(dA), h_end with h0=0 (dt_proj fused).
// xc[16] prefetched into registers (one latency, not 16 serial).
// ---------------------------------------------------------------------------
__global__ __launch_bounds__(512) void scanA(
    const float* __restrict__ XCb, const float* __restrict__ Pdbl,
    const float* __restrict__ A_log, const float* __restrict__ Wdt,
    const float* __restrict__ bdt,
    float* __restrict__ Aprod, float* __restrict__ Hend, int step)
{
    __shared__ float dbl[CL][48];
    int blk = blockIdx.x;           // gb*CH + c
    int c  = blk & (CH - 1);
    int gb = blk >> 6;
    int g  = gb >> 1;
    int lay = g * 2 + step;
    int d = threadIdx.x;
    int r0 = gb * L + c * CL;

    stage_dbl(dbl, Pdbl, r0, threadIdx.x);

    float xc[CL];
    #pragma unroll
    for (int tt = 0; tt < CL; tt++) xc[tt] = XCb[(size_t)(r0 + tt) * DI + d];

    float wdt[16];
    const float* wrow = Wdt + ((size_t)lay * DI + d) * DR;
    #pragma unroll
    for (int k = 0; k < 16; k += 4) {
        float4 v = *(const float4*)&wrow[k];
        wdt[k] = v.x; wdt[k + 1] = v.y; wdt[k + 2] = v.z; wdt[k + 3] = v.w;
    }
    float bias = bdt[(size_t)lay * DI + d];

    float a[DS], h[DS], ap[DS];
    const float* al = A_log + ((size_t)lay * DI + d) * DS;
    #pragma unroll
    for (int s = 0; s < DS; s++) { a[s] = -__expf(al[s]); h[s] = 0.f; ap[s] = 1.f; }
    __syncthreads();

    #pragma unroll
    for (int tt = 0; tt < CL; tt++) {
        float dtr = bias;
        #pragma unroll
        for (int k = 0; k < 16; k++) dtr += dbl[tt][k] * wdt[k];
        float dt = (dtr > 20.f) ? dtr : log1pf(__expf(dtr));
        float dx = dt * xc[tt];
        #pragma unroll
        for (int s = 0; s < DS; s++) {
            float da = __expf(dt * a[s]);
            h[s] = da * h[s] + dx * dbl[tt][16 + s];
            ap[s] *= da;
        }
    }
    size_t base = ((size_t)(gb * DI + d) * CH + c) * DS;
    #pragma unroll
    for (int q = 0; q < 4; q++) {
        *(float4*)&Aprod[base + q * 4] = make_float4(ap[q*4], ap[q*4+1], ap[q*4+2], ap[q*4+3]);
        *(float4*)&Hend [base + q * 4] = make_float4(h[q*4],  h[q*4+1],  h[q*4+2],  h[q*4+3]);
    }
}

// ---------------------------------------------------------------------------
// Combine: serial exclusive scan over 64 chunks per (gb,d,s) lane.
// ---------------------------------------------------------------------------
__global__ __launch_bounds__(256) void scanCombine(
    const float* __restrict__ Aprod, const float* __restrict__ Hend,
    float* __restrict__ Hinit)
{
    int idx = blockIdx.x * 256 + threadIdx.x;  // (gb*DI+d)*DS + s
    int s  = idx & 15;
    int gd = idx >> 4;
    size_t base = (size_t)gd * CH * DS + s;
    float h = 0.f;
    for (int c0 = 0; c0 < CH; c0 += 8) {
        float ap[8], e[8];
        #pragma unroll
        for (int j = 0; j < 8; j++) {
            size_t o = base + (size_t)(c0 + j) * DS;
            ap[j] = Aprod[o]; e[j] = Hend[o];
        }
        #pragma unroll
        for (int j = 0; j < 8; j++) {
            Hinit[base + (size_t)(c0 + j) * DS] = h;
            h = ap[j] * h + e[j];
        }
    }
}

// ---------------------------------------------------------------------------
// Scan phase B + FUSED out_proj (pre-converted weights): replay with h_init,
// y -> LDS (bf16 hi/lo) -> per-wave 3xbf16 MFMA epilogue, K=512 in LDS.
// xc[16]/zz[16] prefetched into registers. YSTR=514 -> conflict-free epilogue.
// OUTMODE 0: write Pout as bf16 hi/lo pairs. OUTMODE 1: scatter fp32 to d_out.
// ---------------------------------------------------------------------------
template<int OUTMODE>
__global__ __launch_bounds__(512) void scanB_fused(
    const float* __restrict__ XCb, const float* __restrict__ Pdbl,
    const float* __restrict__ XZ, const float* __restrict__ A_log,
    const float* __restrict__ Wdt, const float* __restrict__ bdt,
    const float* __restrict__ Dp, const float* __restrict__ Hinit,
    const short* __restrict__ Woh, const short* __restrict__ Wol,
    float* __restrict__ Cout, short* __restrict__ Ph, short* __restrict__ Pl,
    int step)
{
    __shared__ float dbl[CL][48];
    __shared__ short Ys_hi[CL * YSTR];
    __shared__ short Ys_lo[CL * YSTR];
    int blk = blockIdx.x;
    int c  = blk & (CH - 1);
    int gb = blk >> 6;
    int g  = gb >> 1;
    int lay = g * 2 + step;
    int d = threadIdx.x;
    int r0 = gb * L + c * CL;

    stage_dbl(dbl, Pdbl, r0, threadIdx.x);

    float xc[CL], zz[CL];
    #pragma unroll
    for (int tt = 0; tt < CL; tt++) xc[tt] = XCb[(size_t)(r0 + tt) * DI + d];
    #pragma unroll
    for (int tt = 0; tt < CL; tt++) zz[tt] = XZ[(size_t)(r0 + tt) * 1024 + 512 + d];

    float wdt[16];
    const float* wrow = Wdt + ((size_t)lay * DI + d) * DR;
    #pragma unroll
    for (int k = 0; k < 16; k += 4) {
        float4 v = *(const float4*)&wrow[k];
        wdt[k] = v.x; wdt[k + 1] = v.y; wdt[k + 2] = v.z; wdt[k + 3] = v.w;
    }
    float bias = bdt[(size_t)lay * DI + d];

    float a[DS], h[DS];
    const float* al = A_log + ((size_t)lay * DI + d) * DS;
    size_t base = ((size_t)(gb * DI + d) * CH + c) * DS;
    #pragma unroll
    for (int s = 0; s < DS; s++) { a[s] = -__expf(al[s]); h[s] = Hinit[base + s]; }
    float Dv = Dp[(size_t)lay * DI + d];
    __syncthreads();

    #pragma unroll
    for (int tt = 0; tt < CL; tt++) {
        float dtr = bias;
        #pragma unroll
        for (int k = 0; k < 16; k++) dtr += dbl[tt][k] * wdt[k];
        float dt = (dtr > 20.f) ? dtr : log1pf(__expf(dtr));
        float dx = dt * xc[tt];
        float y = 0.f;
        #pragma unroll
        for (int s = 0; s < DS; s++) {
            float da = __expf(dt * a[s]);
            h[s] = da * h[s] + dx * dbl[tt][16 + s];
            y += h[s] * dbl[tt][32 + s];
        }
        y += xc[tt] * Dv;
        y *= silu_f(zz[tt]);
        unsigned short hs = f2bf(y);
        Ys_hi[tt * YSTR + d] = (short)hs;
        Ys_lo[tt * YSTR + d] = (short)f2bf(y - bf2f(hs));
    }
    __syncthreads();

    // ---- fused out_proj epilogue: 16 rows x 256 cols, K=512 ----
    const int lane = threadIdx.x & 63, wv = threadIdx.x >> 6;
    const int m = lane & 15, quad = lane >> 4;
    const size_t wbase = (size_t)lay * DM * DI;

    #pragma unroll
    for (int q = 0; q < 2; q++) {
        const int coln = wv * 32 + q * 16 + m;
        const size_t wrow2 = wbase + (size_t)coln * DI;
        f4x acc = {};
        #pragma unroll
        for (int k0 = 0; k0 < DI; k0 += 32) {
            const int kk = k0 + quad * 8;
            bh8 bhv = *(const bh8*)&Woh[wrow2 + kk];
            bh8 blv = *(const bh8*)&Wol[wrow2 + kk];
            bh8 ahv = *(bh8*)&Ys_hi[m * YSTR + kk];
            bh8 alv = *(bh8*)&Ys_lo[m * YSTR + kk];
            acc = __builtin_amdgcn_mfma_f32_16x16x32_bf16(ahv, bhv, acc, 0, 0, 0);
            acc = __builtin_amdgcn_mfma_f32_16x16x32_bf16(ahv, blv, acc, 0, 0, 0);
            acc = __builtin_amdgcn_mfma_f32_16x16x32_bf16(alv, bhv, acc, 0, 0, 0);
        }
        #pragma unroll
        for (int r = 0; r < 4; r++) {
            int tt = quad * 4 + r;
            int grow = r0 + tt;
            if (OUTMODE == 0) {
                size_t o = (size_t)grow * DM + coln;
                unsigned short hs = f2bf(acc[r]);
                Ph[o] = (short)hs;
                Pl[o] = (short)f2bf(acc[r] - bf2f(hs));
            } else {
                int b = (grow >> 10) & 1, l = grow & 1023;
                size_t dst = (g == 0)
                    ? ((size_t)(b * 1024 + l) * 512 + coln)
                    : ((size_t)(b * 1024 + (1023 - l)) * 512 + 256 + coln);
                Cout[dst] = acc[r];
            }
        }
    }
}

extern "C" void kernel_launch(void* const* d_in, const int* in_sizes, int n_in,
                              void* d_out, int out_size, void* d_ws, size_t ws_size,
                              hipStream_t stream)
{
    const float* x        = (const float*)d_in[0];
    const float* in_proj  = (const float*)d_in[1];
    const float* conv_w   = (const float*)d_in[2];
    const float* conv_b   = (const float*)d_in[3];
    const float* x_proj   = (const float*)d_in[4];
    const float* dt_proj  = (const float*)d_in[5];
    const float* dt_bias  = (const float*)d_in[6];
    const float* A_log    = (const float*)d_in[7];
    const float* Dp       = (const float*)d_in[8];
    const float* out_proj = (const float*)d_in[9];
    float* out = (float*)d_out;

    float* w = (float*)d_ws;
    size_t o = 0;
    float* XZ    = w + o; o += (size_t)RTOT * 1024;
    float* XCb   = w + o; o += (size_t)RTOT * DI;
    float* Pdbl  = w + o; o += (size_t)SKX * RTOT * 48;
    float* Aprod = w + o; o += (size_t)G * BB * DI * CH * DS;
    float* Hend  = w + o; o += (size_t)G * BB * DI * CH * DS;
    float* Hinit = w + o; o += (size_t)G * BB * DI * CH * DS;
    short* Wih   = (short*)(w + o); o += NWIN / 2;
    short* Wil   = (short*)(w + o); o += NWIN / 2;
    short* Woh   = (short*)(w + o); o += NWOUT / 2;
    short* Wol   = (short*)(w + o); o += NWOUT / 2;
    short* Ph    = (short*)(w + o); o += (size_t)RTOT * DM / 2;
    short* Pl    = (short*)(w + o); o += (size_t)RTOT * DM / 2;
    (void)ws_size; (void)in_sizes; (void)n_in; (void)out_size;

    // one-time weight pre-conversion (fp32 -> bf16 hi/lo), single dispatch
    {
        int n4a = NWIN / 4, n4b = NWOUT / 4;
        cvtW2<<<(n4a + n4b + 255) / 256, 256, 0, stream>>>(
            in_proj, Wih, Wil, n4a, out_proj, Woh, Wol, n4b);
    }

    for (int step = 0; step < 2; step++) {
        // in_proj: 4096x1024, K=256, MFMA 3xbf16. 128x64 tiles -> 512 blocks.
        if (step == 0)
            mfma_inproj<1><<<dim3(16, 32), 256, 0, stream>>>(
                x, nullptr, nullptr, Wih, Wil, 0, XZ);
        else
            mfma_inproj<0><<<dim3(16, 32), 256, 0, stream>>>(
                nullptr, Ph, Pl, Wih, Wil, 1, XZ);

        // x_proj (+fused conv+silu, side-writes XCb): split-8 -> 512 blocks.
        gemm_xproj<SKX><<<dim3(1, 64, SKX), 256, 0, stream>>>(
            XZ, conv_w, conv_b, XCb, x_proj, step, Pdbl, (size_t)RTOT * 48);

        // chunked scan: A -> combine -> B(+fused out_proj)
        scanA<<<G * BB * CH, 512, 0, stream>>>(
            XCb, Pdbl, A_log, dt_proj, dt_bias, Aprod, Hend, step);
        scanCombine<<<(G * BB * DI * DS) / 256, 256, 0, stream>>>(Aprod, Hend, Hinit);
        if (step == 0)
            scanB_fused<0><<<G * BB * CH, 512, 0, stream>>>(
                XCb, Pdbl, XZ, A_log, dt_proj, dt_bias, Dp, Hinit,
                Woh, Wol, nullptr, Ph, Pl, 0);
        else
            scanB_fused<1><<<G * BB * CH, 512, 0, stream>>>(
                XCb, Pdbl, XZ, A_log, dt_proj, dt_bias, Dp, Hinit,
                Woh, Wol, out, nullptr, nullptr, 1);
    }
}

// Round 13
// 291.514 us; speedup vs baseline: 1.0327x; 1.0327x over previous
//
#include <hip/hip_runtime.h>
#include <math.h>

#define G 2
#define BB 2
#define L 1024
#define DM 256
#define DI 512
#define DS 16
#define DR 16
#define CH 128             // chunks per sequence
#define CL 8               // L / CH (halved: 2 blocks/CU, shorter serial chain)
#define RTOT (G*BB*L)      // 4096 rows per layer-step
#define SKX 8              // x_proj split-K factor
#define YSTR 520           // Ys LDS row stride (shorts); 514 DOUBLED conflicts (r12)

#define NWIN  (4 * 2 * DI * DM)   // in_proj elements (4 layers)
#define NWOUT (4 * DM * DI)       // out_proj elements

typedef short bh8 __attribute__((ext_vector_type(8)));
typedef float f4x __attribute__((ext_vector_type(4)));

__device__ __forceinline__ float silu_f(float x) { return x / (1.f + __expf(-x)); }

__device__ __forceinline__ unsigned short f2bf(float f) {
    unsigned u = __float_as_uint(f);
    unsigned r = u + 0x7FFFu + ((u >> 16) & 1u);
    return (unsigned short)(r >> 16);
}
__device__ __forceinline__ float bf2f(unsigned short s) {
    return __uint_as_float(((unsigned)s) << 16);
}

// ---------------------------------------------------------------------------
// One-time weight pre-conversion (both weight arrays in ONE dispatch):
// fp32 -> (bf16 hi, bf16 lo) pairs.
// ---------------------------------------------------------------------------
__global__ __launch_bounds__(256) void cvtW2(
    const float* __restrict__ Wa, short* __restrict__ Wah, short* __restrict__ Wal, int n4a,
    const float* __restrict__ Wb, short* __restrict__ Wbh, short* __restrict__ Wbl, int n4b)
{
    int i = blockIdx.x * 256 + threadIdx.x;
    const float* W; short *Wh, *Wl;
    if (i < n4a) { W = Wa; Wh = Wah; Wl = Wal; }
    else if (i < n4a + n4b) { i -= n4a; W = Wb; Wh = Wbh; Wl = Wbl; }
    else return;
    float4 v = *(const float4*)&W[(size_t)i * 4];
    short4 h, l;
    unsigned short s;
    s = f2bf(v.x); h.x = (short)s; l.x = (short)f2bf(v.x - bf2f(s));
    s = f2bf(v.y); h.y = (short)s; l.y = (short)f2bf(v.y - bf2f(s));
    s = f2bf(v.z); h.z = (short)s; l.z = (short)f2bf(v.z - bf2f(s));
    s = f2bf(v.w); h.w = (short)s; l.w = (short)f2bf(v.w - bf2f(s));
    *(short4*)&Wh[(size_t)i * 4] = h;
    *(short4*)&Wl[(size_t)i * 4] = l;
}

// ---------------------------------------------------------------------------
// in_proj MFMA GEMM (3xbf16). BM=128, N=1024, K=256.
// AMAP 1: A = x (fp32) with g-dependent time reversal (step 0).
// AMAP 0: A = Pout as pre-split bf16 hi/lo (step 1) - cvt-free staging.
// ---------------------------------------------------------------------------
template<int AMAP>
__global__ __launch_bounds__(256) void mfma_inproj(
    const float* __restrict__ Ax,
    const short* __restrict__ Ah, const short* __restrict__ Al,
    const short* __restrict__ Wh, const short* __restrict__ Wl,
    int step, float* __restrict__ C)
{
    constexpr int BM = 128, Ktot = DM, Nout = 2 * DI, ldc = 1024;
    __shared__ short As_hi[BM * 40];
    __shared__ short As_lo[BM * 40];
    __shared__ short Bs_hi[64 * 40];
    __shared__ short Bs_lo[64 * 40];

    const int row0 = blockIdx.y * BM;
    const int col0 = blockIdx.x * 64;
    const int g    = row0 >> 11;
    const int lay  = g * 2 + step;
    const short* Whg = Wh + (size_t)lay * Nout * Ktot;
    const short* Wlg = Wl + (size_t)lay * Nout * Ktot;
    const int t    = threadIdx.x;
    const int lane = t & 63, wv = t >> 6;
    const int m = lane & 15, quad = lane >> 4;
    const int wr = wv >> 1, wc = wv & 1;
    const int NT = Ktot / 32;     // 8

    float4 pa[4];
    short4 pah[4], pal[4], pbh[2], pbl[2];
    auto loadT = [&](int kt) {
        const int kb = kt * 32;
        #pragma unroll
        for (int i = 0; i < 4; i++) {
            int id = t + 256 * i;
            int row = id >> 3, kq = id & 7;
            if (AMAP == 1) {
                int gr = row0 + row;
                int gg = gr >> 11, b = (gr >> 10) & 1, l = gr & 1023;
                int sl = gg ? (1023 - l) : l;
                pa[i] = *(const float4*)&Ax[(size_t)(b * 1024 + sl) * Ktot + kb + kq * 4];
            } else {
                size_t o = (size_t)(row0 + row) * Ktot + kb + kq * 4;
                pah[i] = *(const short4*)&Ah[o];
                pal[i] = *(const short4*)&Al[o];
            }
        }
        #pragma unroll
        for (int i = 0; i < 2; i++) {
            int id = t + 256 * i;
            int row = id >> 3, kq = id & 7;
            size_t o = (size_t)(col0 + row) * Ktot + kb + kq * 4;
            pbh[i] = *(const short4*)&Whg[o];
            pbl[i] = *(const short4*)&Wlg[o];
        }
    };

    f4x acc[4][2] = {};
    loadT(0);

    for (int kt = 0; kt < NT; kt++) {
        #pragma unroll
        for (int i = 0; i < 4; i++) {
            int id = t + 256 * i;
            int row = id >> 3, kq = id & 7;
            if (AMAP == 1) {
                float4 v = pa[i];
                short4 h, l;
                unsigned short s;
                s = f2bf(v.x); h.x = (short)s; l.x = (short)f2bf(v.x - bf2f(s));
                s = f2bf(v.y); h.y = (short)s; l.y = (short)f2bf(v.y - bf2f(s));
                s = f2bf(v.z); h.z = (short)s; l.z = (short)f2bf(v.z - bf2f(s));
                s = f2bf(v.w); h.w = (short)s; l.w = (short)f2bf(v.w - bf2f(s));
                *(short4*)&As_hi[row * 40 + kq * 4] = h;
                *(short4*)&As_lo[row * 40 + kq * 4] = l;
            } else {
                *(short4*)&As_hi[row * 40 + kq * 4] = pah[i];
                *(short4*)&As_lo[row * 40 + kq * 4] = pal[i];
            }
        }
        #pragma unroll
        for (int i = 0; i < 2; i++) {
            int id = t + 256 * i;
            int row = id >> 3, kq = id & 7;
            *(short4*)&Bs_hi[row * 40 + kq * 4] = pbh[i];
            *(short4*)&Bs_lo[row * 40 + kq * 4] = pbl[i];
        }
        __syncthreads();
        if (kt + 1 < NT) loadT(kt + 1);

        bh8 ah[4], al[4], bh[2], bl[2];
        #pragma unroll
        for (int p = 0; p < 4; p++) {
            int r = wr * 64 + p * 16 + m;
            ah[p] = *(bh8*)&As_hi[r * 40 + quad * 8];
            al[p] = *(bh8*)&As_lo[r * 40 + quad * 8];
        }
        #pragma unroll
        for (int q = 0; q < 2; q++) {
            int r = wc * 32 + q * 16 + m;
            bh[q] = *(bh8*)&Bs_hi[r * 40 + quad * 8];
            bl[q] = *(bh8*)&Bs_lo[r * 40 + quad * 8];
        }
        #pragma unroll
        for (int p = 0; p < 4; p++)
            #pragma unroll
            for (int q = 0; q < 2; q++) {
                acc[p][q] = __builtin_amdgcn_mfma_f32_16x16x32_bf16(ah[p], bh[q], acc[p][q], 0, 0, 0);
                acc[p][q] = __builtin_amdgcn_mfma_f32_16x16x32_bf16(ah[p], bl[q], acc[p][q], 0, 0, 0);
                acc[p][q] = __builtin_amdgcn_mfma_f32_16x16x32_bf16(al[p], bh[q], acc[p][q], 0, 0, 0);
            }
        __syncthreads();
    }

    #pragma unroll
    for (int p = 0; p < 4; p++)
        #pragma unroll
        for (int q = 0; q < 2; q++) {
            int gcol = col0 + wc * 32 + q * 16 + m;
            #pragma unroll
            for (int r = 0; r < 4; r++) {
                int grow = row0 + wr * 64 + p * 16 + quad * 4 + r;
                C[(size_t)grow * ldc + gcol] = acc[p][q][r];
            }
        }
}

// ---------------------------------------------------------------------------
// x_proj GEMM (fp32) with the depthwise conv+silu FUSED into the A-staging.
// ---------------------------------------------------------------------------
template<int SPLITK>
__global__ __launch_bounds__(256) void gemm_xproj(
    const float* __restrict__ XZ, const float* __restrict__ cw,
    const float* __restrict__ cb, float* __restrict__ XCb,
    const float* __restrict__ W, int step,
    float* __restrict__ C, size_t partStride)
{
    constexpr int Nout = 48, Ktot = DI;
    __shared__ float As[16][68];
    __shared__ float Bs[16][68];

    const int row0 = blockIdx.y * 64;
    const int g    = row0 >> 11;
    const int lay  = g * 2 + step;
    const float* Wg = W + (size_t)lay * Nout * Ktot;
    const int t  = threadIdx.x;
    const int tx = t & 15, ty = t >> 4;
    const int Kc    = Ktot / SPLITK;
    const int kbase = blockIdx.z * Kc;
    const int NT    = Kc / 16;

    const int sr = t >> 2;
    const int sk = (t & 3) * 4;
    const int gr = row0 + sr;
    const int l  = gr & 1023;
    const bool bok = (sr < Nout);

    float4 pa, pb;
    auto loadT = [&](int kt) {
        const int ch = kbase + kt * 16 + sk;
        const float* wb = cw + ((size_t)lay * 512 + ch) * 4;
        float4 w0 = *(const float4*)&wb[0];
        float4 w1 = *(const float4*)&wb[4];
        float4 w2 = *(const float4*)&wb[8];
        float4 w3 = *(const float4*)&wb[12];
        float4 acc = *(const float4*)&cb[(size_t)lay * 512 + ch];
        #pragma unroll
        for (int k = 0; k < 4; k++) {
            if (l - 3 + k < 0) continue;
            float4 xv = *(const float4*)&XZ[(size_t)(gr - 3 + k) * 1024 + ch];
            acc.x += (&w0.x)[k] * xv.x; acc.y += (&w1.x)[k] * xv.y;
            acc.z += (&w2.x)[k] * xv.z; acc.w += (&w3.x)[k] * xv.w;
        }
        acc.x = silu_f(acc.x); acc.y = silu_f(acc.y);
        acc.z = silu_f(acc.z); acc.w = silu_f(acc.w);
        pa = acc;
        *(float4*)&XCb[(size_t)gr * 512 + ch] = acc;     // side product
        pb = bok ? *(const float4*)&Wg[(size_t)sr * Ktot + kbase + kt * 16 + sk]
                 : make_float4(0.f, 0.f, 0.f, 0.f);
    };

    float acc[4][4] = {};
    loadT(0);

    for (int kt = 0; kt < NT; kt++) {
        As[sk + 0][sr] = pa.x; As[sk + 1][sr] = pa.y;
        As[sk + 2][sr] = pa.z; As[sk + 3][sr] = pa.w;
        Bs[sk + 0][sr] = pb.x; Bs[sk + 1][sr] = pb.y;
        Bs[sk + 2][sr] = pb.z; Bs[sk + 3][sr] = pb.w;
        __syncthreads();
        if (kt + 1 < NT) loadT(kt + 1);
        #pragma unroll
        for (int kk = 0; kk < 16; kk++) {
            float4 a = *(const float4*)&As[kk][ty * 4];
            float4 b = *(const float4*)&Bs[kk][tx * 4];
            float av[4] = {a.x, a.y, a.z, a.w};
            float bv[4] = {b.x, b.y, b.z, b.w};
            #pragma unroll
            for (int i = 0; i < 4; i++)
                #pragma unroll
                for (int j = 0; j < 4; j++) acc[i][j] += av[i] * bv[j];
        }
        __syncthreads();
    }

    float* Cz = C + (size_t)blockIdx.z * partStride;
    const int col = tx * 4;
    if (col < Nout) {
        #pragma unroll
        for (int i = 0; i < 4; i++) {
            int r = row0 + ty * 4 + i;
            *(float4*)&Cz[(size_t)r * 48 + col] =
                make_float4(acc[i][0], acc[i][1], acc[i][2], acc[i][3]);
        }
    }
}

// ---------------------------------------------------------------------------
// Stage dbl chunk (summing the SKX x_proj slabs) into LDS.
// ---------------------------------------------------------------------------
__device__ __forceinline__ void stage_dbl(
    float dbl[CL][48], const float* __restrict__ Pdbl, int r0, int tid)
{
    if (tid < CL * 48) {
        int rr = tid / 48, cc = tid - rr * 48;
        size_t o = (size_t)(r0 + rr) * 48 + cc;
        float v = 0.f;
        #pragma unroll
        for (int s = 0; s < SKX; s++) v += Pdbl[(size_t)s * (RTOT * 48) + o];
        dbl[rr][cc] = v;
    }
}

// ---------------------------------------------------------------------------
// Scan phase A: per (gb,chunk,d) -> prod(dA), h_end with h0=0 (dt_proj fused).
// CL=8: plain loop (round-12's unroll+prefetch spilled -> 75MB scratch).
// ---------------------------------------------------------------------------
__global__ __launch_bounds__(512) void scanA(
    const float* __restrict__ XCb, const float* __restrict__ Pdbl,
    const float* __restrict__ A_log, const float* __restrict__ Wdt,
    const float* __restrict__ bdt,
    float* __restrict__ Aprod, float* __restrict__ Hend, int step)
{
    __shared__ float dbl[CL][48];
    int blk = blockIdx.x;           // gb*CH + c
    int c  = blk & (CH - 1);
    int gb = blk >> 7;
    int g  = gb >> 1;
    int lay = g * 2 + step;
    int d = threadIdx.x;
    int r0 = gb * L + c * CL;

    stage_dbl(dbl, Pdbl, r0, threadIdx.x);

    float wdt[16];
    const float* wrow = Wdt + ((size_t)lay * DI + d) * DR;
    #pragma unroll
    for (int k = 0; k < 16; k += 4) {
        float4 v = *(const float4*)&wrow[k];
        wdt[k] = v.x; wdt[k + 1] = v.y; wdt[k + 2] = v.z; wdt[k + 3] = v.w;
    }
    float bias = bdt[(size_t)lay * DI + d];

    float a[DS], h[DS], ap[DS];
    const float* al = A_log + ((size_t)lay * DI + d) * DS;
    #pragma unroll
    for (int s = 0; s < DS; s++) { a[s] = -__expf(al[s]); h[s] = 0.f; ap[s] = 1.f; }
    __syncthreads();

    for (int tt = 0; tt < CL; tt++) {
        float dtr = bias;
        #pragma unroll
        for (int k = 0; k < 16; k++) dtr += dbl[tt][k] * wdt[k];
        float dt = (dtr > 20.f) ? dtr : log1pf(__expf(dtr));
        float xc = XCb[(size_t)(r0 + tt) * DI + d];
        float dx = dt * xc;
        #pragma unroll
        for (int s = 0; s < DS; s++) {
            float da = __expf(dt * a[s]);
            h[s] = da * h[s] + dx * dbl[tt][16 + s];
            ap[s] *= da;
        }
    }
    size_t base = ((size_t)(gb * DI + d) * CH + c) * DS;
    #pragma unroll
    for (int q = 0; q < 4; q++) {
        *(float4*)&Aprod[base + q * 4] = make_float4(ap[q*4], ap[q*4+1], ap[q*4+2], ap[q*4+3]);
        *(float4*)&Hend [base + q * 4] = make_float4(h[q*4],  h[q*4+1],  h[q*4+2],  h[q*4+3]);
    }
}

// ---------------------------------------------------------------------------
// Combine: serial exclusive scan over CH chunks per (gb,d,s) lane.
// ---------------------------------------------------------------------------
__global__ __launch_bounds__(256) void scanCombine(
    const float* __restrict__ Aprod, const float* __restrict__ Hend,
    float* __restrict__ Hinit)
{
    int idx = blockIdx.x * 256 + threadIdx.x;  // (gb*DI+d)*DS + s
    int s  = idx & 15;
    int gd = idx >> 4;
    size_t base = (size_t)gd * CH * DS + s;
    float h = 0.f;
    for (int c0 = 0; c0 < CH; c0 += 8) {
        float ap[8], e[8];
        #pragma unroll
        for (int j = 0; j < 8; j++) {
            size_t o = base + (size_t)(c0 + j) * DS;
            ap[j] = Aprod[o]; e[j] = Hend[o];
        }
        #pragma unroll
        for (int j = 0; j < 8; j++) {
            Hinit[base + (size_t)(c0 + j) * DS] = h;
            h = ap[j] * h + e[j];
        }
    }
}

// ---------------------------------------------------------------------------
// Scan phase B + FUSED out_proj: CL=8 rows/block (2 blocks/CU). Ys rows 8..15
// zero-padded so the 16x16 MFMA epilogue stays valid; stores guarded to tt<8.
// OUTMODE 0: write Pout as bf16 hi/lo pairs. OUTMODE 1: scatter fp32 to d_out.
// ---------------------------------------------------------------------------
template<int OUTMODE>
__global__ __launch_bounds__(512) void scanB_fused(
    const float* __restrict__ XCb, const float* __restrict__ Pdbl,
    const float* __restrict__ XZ, const float* __restrict__ A_log,
    const float* __restrict__ Wdt, const float* __restrict__ bdt,
    const float* __restrict__ Dp, const float* __restrict__ Hinit,
    const short* __restrict__ Woh, const short* __restrict__ Wol,
    float* __restrict__ Cout, short* __restrict__ Ph, short* __restrict__ Pl,
    int step)
{
    __shared__ float dbl[CL][48];
    __shared__ short Ys_hi[16 * YSTR];
    __shared__ short Ys_lo[16 * YSTR];
    int blk = blockIdx.x;
    int c  = blk & (CH - 1);
    int gb = blk >> 7;
    int g  = gb >> 1;
    int lay = g * 2 + step;
    int d = threadIdx.x;
    int r0 = gb * L + c * CL;

    stage_dbl(dbl, Pdbl, r0, threadIdx.x);

    // zero-pad Ys rows CL..15 (MFMA reads all 16 m-rows)
    #pragma unroll
    for (int j = CL; j < 16; j++) {
        Ys_hi[j * YSTR + d] = 0;
        Ys_lo[j * YSTR + d] = 0;
    }

    float xc[CL], zz[CL];
    #pragma unroll
    for (int tt = 0; tt < CL; tt++) xc[tt] = XCb[(size_t)(r0 + tt) * DI + d];
    #pragma unroll
    for (int tt = 0; tt < CL; tt++) zz[tt] = XZ[(size_t)(r0 + tt) * 1024 + 512 + d];

    float wdt[16];
    const float* wrow = Wdt + ((size_t)lay * DI + d) * DR;
    #pragma unroll
    for (int k = 0; k < 16; k += 4) {
        float4 v = *(const float4*)&wrow[k];
        wdt[k] = v.x; wdt[k + 1] = v.y; wdt[k + 2] = v.z; wdt[k + 3] = v.w;
    }
    float bias = bdt[(size_t)lay * DI + d];

    float a[DS], h[DS];
    const float* al = A_log + ((size_t)lay * DI + d) * DS;
    size_t base = ((size_t)(gb * DI + d) * CH + c) * DS;
    #pragma unroll
    for (int s = 0; s < DS; s++) { a[s] = -__expf(al[s]); h[s] = Hinit[base + s]; }
    float Dv = Dp[(size_t)lay * DI + d];
    __syncthreads();

    #pragma unroll
    for (int tt = 0; tt < CL; tt++) {
        float dtr = bias;
        #pragma unroll
        for (int k = 0; k < 16; k++) dtr += dbl[tt][k] * wdt[k];
        float dt = (dtr > 20.f) ? dtr : log1pf(__expf(dtr));
        float dx = dt * xc[tt];
        float y = 0.f;
        #pragma unroll
        for (int s = 0; s < DS; s++) {
            float da = __expf(dt * a[s]);
            h[s] = da * h[s] + dx * dbl[tt][16 + s];
            y += h[s] * dbl[tt][32 + s];
        }
        y += xc[tt] * Dv;
        y *= silu_f(zz[tt]);
        unsigned short hs = f2bf(y);
        Ys_hi[tt * YSTR + d] = (short)hs;
        Ys_lo[tt * YSTR + d] = (short)f2bf(y - bf2f(hs));
    }
    __syncthreads();

    // ---- fused out_proj epilogue: CL rows x 256 cols, K=512 ----
    const int lane = threadIdx.x & 63, wv = threadIdx.x >> 6;
    const int m = lane & 15, quad = lane >> 4;
    const size_t wbase = (size_t)lay * DM * DI;

    #pragma unroll
    for (int q = 0; q < 2; q++) {
        const int coln = wv * 32 + q * 16 + m;
        const size_t wrow2 = wbase + (size_t)coln * DI;
        f4x acc = {};
        #pragma unroll
        for (int k0 = 0; k0 < DI; k0 += 32) {
            const int kk = k0 + quad * 8;
            bh8 bhv = *(const bh8*)&Woh[wrow2 + kk];
            bh8 blv = *(const bh8*)&Wol[wrow2 + kk];
            bh8 ahv = *(bh8*)&Ys_hi[m * YSTR + kk];
            bh8 alv = *(bh8*)&Ys_lo[m * YSTR + kk];
            acc = __builtin_amdgcn_mfma_f32_16x16x32_bf16(ahv, bhv, acc, 0, 0, 0);
            acc = __builtin_amdgcn_mfma_f32_16x16x32_bf16(ahv, blv, acc, 0, 0, 0);
            acc = __builtin_amdgcn_mfma_f32_16x16x32_bf16(alv, bhv, acc, 0, 0, 0);
        }
        #pragma unroll
        for (int r = 0; r < 4; r++) {
            int tt = quad * 4 + r;
            if (tt >= CL) continue;
            int grow = r0 + tt;
            if (OUTMODE == 0) {
                size_t o = (size_t)grow * DM + coln;
                unsigned short hs = f2bf(acc[r]);
                Ph[o] = (short)hs;
                Pl[o] = (short)f2bf(acc[r] - bf2f(hs));
            } else {
                int b = (grow >> 10) & 1, l = grow & 1023;
                size_t dst = (g == 0)
                    ? ((size_t)(b * 1024 + l) * 512 + coln)
                    : ((size_t)(b * 1024 + (1023 - l)) * 512 + 256 + coln);
                Cout[dst] = acc[r];
            }
        }
    }
}

extern "C" void kernel_launch(void* const* d_in, const int* in_sizes, int n_in,
                              void* d_out, int out_size, void* d_ws, size_t ws_size,
                              hipStream_t stream)
{
    const float* x        = (const float*)d_in[0];
    const float* in_proj  = (const float*)d_in[1];
    const float* conv_w   = (const float*)d_in[2];
    const float* conv_b   = (const float*)d_in[3];
    const float* x_proj   = (const float*)d_in[4];
    const float* dt_proj  = (const float*)d_in[5];
    const float* dt_bias  = (const float*)d_in[6];
    const float* A_log    = (const float*)d_in[7];
    const float* Dp       = (const float*)d_in[8];
    const float* out_proj = (const float*)d_in[9];
    float* out = (float*)d_out;

    float* w = (float*)d_ws;
    size_t o = 0;
    float* XZ    = w + o; o += (size_t)RTOT * 1024;
    float* XCb   = w + o; o += (size_t)RTOT * DI;
    float* Pdbl  = w + o; o += (size_t)SKX * RTOT * 48;
    float* Aprod = w + o; o += (size_t)G * BB * DI * CH * DS;   // 16.8 MB
    float* Hend  = w + o; o += (size_t)G * BB * DI * CH * DS;
    float* Hinit = w + o; o += (size_t)G * BB * DI * CH * DS;
    short* Wih   = (short*)(w + o); o += NWIN / 2;
    short* Wil   = (short*)(w + o); o += NWIN / 2;
    short* Woh   = (short*)(w + o); o += NWOUT / 2;
    short* Wol   = (short*)(w + o); o += NWOUT / 2;
    short* Ph    = (short*)(w + o); o += (size_t)RTOT * DM / 2;
    short* Pl    = (short*)(w + o); o += (size_t)RTOT * DM / 2;
    (void)ws_size; (void)in_sizes; (void)n_in; (void)out_size;

    // one-time weight pre-conversion (fp32 -> bf16 hi/lo), single dispatch
    {
        int n4a = NWIN / 4, n4b = NWOUT / 4;
        cvtW2<<<(n4a + n4b + 255) / 256, 256, 0, stream>>>(
            in_proj, Wih, Wil, n4a, out_proj, Woh, Wol, n4b);
    }

    for (int step = 0; step < 2; step++) {
        // in_proj: 4096x1024, K=256, MFMA 3xbf16. 128x64 tiles -> 512 blocks.
        if (step == 0)
            mfma_inproj<1><<<dim3(16, 32), 256, 0, stream>>>(
                x, nullptr, nullptr, Wih, Wil, 0, XZ);
        else
            mfma_inproj<0><<<dim3(16, 32), 256, 0, stream>>>(
                nullptr, Ph, Pl, Wih, Wil, 1, XZ);

        // x_proj (+fused conv+silu, side-writes XCb): split-8 -> 512 blocks.
        gemm_xproj<SKX><<<dim3(1, 64, SKX), 256, 0, stream>>>(
            XZ, conv_w, conv_b, XCb, x_proj, step, Pdbl, (size_t)RTOT * 48);

        // chunked scan, CL=8: A -> combine -> B(+fused out_proj); 512 blocks.
        scanA<<<G * BB * CH, 512, 0, stream>>>(
            XCb, Pdbl, A_log, dt_proj, dt_bias, Aprod, Hend, step);
        scanCombine<<<(G * BB * DI * DS) / 256, 256, 0, stream>>>(Aprod, Hend, Hinit);
        if (step == 0)
            scanB_fused<0><<<G * BB * CH, 512, 0, stream>>>(
                XCb, Pdbl, XZ, A_log, dt_proj, dt_bias, Dp, Hinit,
                Woh, Wol, nullptr, Ph, Pl, 0);
        else
            scanB_fused<1><<<G * BB * CH, 512, 0, stream>>>(
                XCb, Pdbl, XZ, A_log, dt_proj, dt_bias, Dp, Hinit,
                Woh, Wol, out, nullptr, nullptr, 1);
    }
}

// Round 14
// 243.583 us; speedup vs baseline: 1.2360x; 1.1968x over previous
//
#include <hip/hip_runtime.h>
#include <math.h>

#define G 2
#define BB 2
#define L 1024
#define DM 256
#define DI 512
#define DS 16
#define DR 16
#define CH 64              // chunks per sequence (128 doubled epilogue work - r13)
#define CL 16              // L / CH
#define RTOT (G*BB*L)      // 4096 rows per layer-step
#define SKX 8              // x_proj split-K factor
#define YSTR 520           // Ys LDS row stride (shorts); 514 doubled conflicts (r12)

#define NWIN  (4 * 2 * DI * DM)   // in_proj elements (4 layers)
#define NWOUT (4 * DM * DI)       // out_proj elements

typedef short bh8 __attribute__((ext_vector_type(8)));
typedef float f4x __attribute__((ext_vector_type(4)));

__device__ __forceinline__ float silu_f(float x) { return x / (1.f + __expf(-x)); }
// fast softplus: log1pf is a precise libm expansion (~dozens of VALU ops);
// __logf(1+e) is 2 transcendentals. |err| ~1e-7 rel, fine at 6x margin.
__device__ __forceinline__ float softplus_f(float x) {
    return (x > 20.f) ? x : __logf(1.f + __expf(x));
}

__device__ __forceinline__ unsigned short f2bf(float f) {
    unsigned u = __float_as_uint(f);
    unsigned r = u + 0x7FFFu + ((u >> 16) & 1u);
    return (unsigned short)(r >> 16);
}
__device__ __forceinline__ float bf2f(unsigned short s) {
    return __uint_as_float(((unsigned)s) << 16);
}

// ---------------------------------------------------------------------------
// One-time weight pre-conversion (both weight arrays in ONE dispatch):
// fp32 -> (bf16 hi, bf16 lo) pairs.
// ---------------------------------------------------------------------------
__global__ __launch_bounds__(256) void cvtW2(
    const float* __restrict__ Wa, short* __restrict__ Wah, short* __restrict__ Wal, int n4a,
    const float* __restrict__ Wb, short* __restrict__ Wbh, short* __restrict__ Wbl, int n4b)
{
    int i = blockIdx.x * 256 + threadIdx.x;
    const float* W; short *Wh, *Wl;
    if (i < n4a) { W = Wa; Wh = Wah; Wl = Wal; }
    else if (i < n4a + n4b) { i -= n4a; W = Wb; Wh = Wbh; Wl = Wbl; }
    else return;
    float4 v = *(const float4*)&W[(size_t)i * 4];
    short4 h, l;
    unsigned short s;
    s = f2bf(v.x); h.x = (short)s; l.x = (short)f2bf(v.x - bf2f(s));
    s = f2bf(v.y); h.y = (short)s; l.y = (short)f2bf(v.y - bf2f(s));
    s = f2bf(v.z); h.z = (short)s; l.z = (short)f2bf(v.z - bf2f(s));
    s = f2bf(v.w); h.w = (short)s; l.w = (short)f2bf(v.w - bf2f(s));
    *(short4*)&Wh[(size_t)i * 4] = h;
    *(short4*)&Wl[(size_t)i * 4] = l;
}

// ---------------------------------------------------------------------------
// in_proj MFMA GEMM (3xbf16). BM=128, N=1024, K=256.
// AMAP 1: A = x (fp32) with g-dependent time reversal (step 0).
// AMAP 0: A = Pout as pre-split bf16 hi/lo (step 1) - cvt-free staging.
// ---------------------------------------------------------------------------
template<int AMAP>
__global__ __launch_bounds__(256) void mfma_inproj(
    const float* __restrict__ Ax,
    const short* __restrict__ Ah, const short* __restrict__ Al,
    const short* __restrict__ Wh, const short* __restrict__ Wl,
    int step, float* __restrict__ C)
{
    constexpr int BM = 128, Ktot = DM, Nout = 2 * DI, ldc = 1024;
    __shared__ short As_hi[BM * 40];
    __shared__ short As_lo[BM * 40];
    __shared__ short Bs_hi[64 * 40];
    __shared__ short Bs_lo[64 * 40];

    const int row0 = blockIdx.y * BM;
    const int col0 = blockIdx.x * 64;
    const int g    = row0 >> 11;
    const int lay  = g * 2 + step;
    const short* Whg = Wh + (size_t)lay * Nout * Ktot;
    const short* Wlg = Wl + (size_t)lay * Nout * Ktot;
    const int t    = threadIdx.x;
    const int lane = t & 63, wv = t >> 6;
    const int m = lane & 15, quad = lane >> 4;
    const int wr = wv >> 1, wc = wv & 1;
    const int NT = Ktot / 32;     // 8

    float4 pa[4];
    short4 pah[4], pal[4], pbh[2], pbl[2];
    auto loadT = [&](int kt) {
        const int kb = kt * 32;
        #pragma unroll
        for (int i = 0; i < 4; i++) {
            int id = t + 256 * i;
            int row = id >> 3, kq = id & 7;
            if (AMAP == 1) {
                int gr = row0 + row;
                int gg = gr >> 11, b = (gr >> 10) & 1, l = gr & 1023;
                int sl = gg ? (1023 - l) : l;
                pa[i] = *(const float4*)&Ax[(size_t)(b * 1024 + sl) * Ktot + kb + kq * 4];
            } else {
                size_t o = (size_t)(row0 + row) * Ktot + kb + kq * 4;
                pah[i] = *(const short4*)&Ah[o];
                pal[i] = *(const short4*)&Al[o];
            }
        }
        #pragma unroll
        for (int i = 0; i < 2; i++) {
            int id = t + 256 * i;
            int row = id >> 3, kq = id & 7;
            size_t o = (size_t)(col0 + row) * Ktot + kb + kq * 4;
            pbh[i] = *(const short4*)&Whg[o];
            pbl[i] = *(const short4*)&Wlg[o];
        }
    };

    f4x acc[4][2] = {};
    loadT(0);

    for (int kt = 0; kt < NT; kt++) {
        #pragma unroll
        for (int i = 0; i < 4; i++) {
            int id = t + 256 * i;
            int row = id >> 3, kq = id & 7;
            if (AMAP == 1) {
                float4 v = pa[i];
                short4 h, l;
                unsigned short s;
                s = f2bf(v.x); h.x = (short)s; l.x = (short)f2bf(v.x - bf2f(s));
                s = f2bf(v.y); h.y = (short)s; l.y = (short)f2bf(v.y - bf2f(s));
                s = f2bf(v.z); h.z = (short)s; l.z = (short)f2bf(v.z - bf2f(s));
                s = f2bf(v.w); h.w = (short)s; l.w = (short)f2bf(v.w - bf2f(s));
                *(short4*)&As_hi[row * 40 + kq * 4] = h;
                *(short4*)&As_lo[row * 40 + kq * 4] = l;
            } else {
                *(short4*)&As_hi[row * 40 + kq * 4] = pah[i];
                *(short4*)&As_lo[row * 40 + kq * 4] = pal[i];
            }
        }
        #pragma unroll
        for (int i = 0; i < 2; i++) {
            int id = t + 256 * i;
            int row = id >> 3, kq = id & 7;
            *(short4*)&Bs_hi[row * 40 + kq * 4] = pbh[i];
            *(short4*)&Bs_lo[row * 40 + kq * 4] = pbl[i];
        }
        __syncthreads();
        if (kt + 1 < NT) loadT(kt + 1);

        bh8 ah[4], al[4], bh[2], bl[2];
        #pragma unroll
        for (int p = 0; p < 4; p++) {
            int r = wr * 64 + p * 16 + m;
            ah[p] = *(bh8*)&As_hi[r * 40 + quad * 8];
            al[p] = *(bh8*)&As_lo[r * 40 + quad * 8];
        }
        #pragma unroll
        for (int q = 0; q < 2; q++) {
            int r = wc * 32 + q * 16 + m;
            bh[q] = *(bh8*)&Bs_hi[r * 40 + quad * 8];
            bl[q] = *(bh8*)&Bs_lo[r * 40 + quad * 8];
        }
        #pragma unroll
        for (int p = 0; p < 4; p++)
            #pragma unroll
            for (int q = 0; q < 2; q++) {
                acc[p][q] = __builtin_amdgcn_mfma_f32_16x16x32_bf16(ah[p], bh[q], acc[p][q], 0, 0, 0);
                acc[p][q] = __builtin_amdgcn_mfma_f32_16x16x32_bf16(ah[p], bl[q], acc[p][q], 0, 0, 0);
                acc[p][q] = __builtin_amdgcn_mfma_f32_16x16x32_bf16(al[p], bh[q], acc[p][q], 0, 0, 0);
            }
        __syncthreads();
    }

    #pragma unroll
    for (int p = 0; p < 4; p++)
        #pragma unroll
        for (int q = 0; q < 2; q++) {
            int gcol = col0 + wc * 32 + q * 16 + m;
            #pragma unroll
            for (int r = 0; r < 4; r++) {
                int grow = row0 + wr * 64 + p * 16 + quad * 4 + r;
                C[(size_t)grow * ldc + gcol] = acc[p][q][r];
            }
        }
}

// ---------------------------------------------------------------------------
// x_proj GEMM (fp32) with the depthwise conv+silu FUSED into the A-staging.
// ---------------------------------------------------------------------------
template<int SPLITK>
__global__ __launch_bounds__(256) void gemm_xproj(
    const float* __restrict__ XZ, const float* __restrict__ cw,
    const float* __restrict__ cb, float* __restrict__ XCb,
    const float* __restrict__ W, int step,
    float* __restrict__ C, size_t partStride)
{
    constexpr int Nout = 48, Ktot = DI;
    __shared__ float As[16][68];
    __shared__ float Bs[16][68];

    const int row0 = blockIdx.y * 64;
    const int g    = row0 >> 11;
    const int lay  = g * 2 + step;
    const float* Wg = W + (size_t)lay * Nout * Ktot;
    const int t  = threadIdx.x;
    const int tx = t & 15, ty = t >> 4;
    const int Kc    = Ktot / SPLITK;
    const int kbase = blockIdx.z * Kc;
    const int NT    = Kc / 16;

    const int sr = t >> 2;
    const int sk = (t & 3) * 4;
    const int gr = row0 + sr;
    const int l  = gr & 1023;
    const bool bok = (sr < Nout);

    float4 pa, pb;
    auto loadT = [&](int kt) {
        const int ch = kbase + kt * 16 + sk;
        const float* wb = cw + ((size_t)lay * 512 + ch) * 4;
        float4 w0 = *(const float4*)&wb[0];
        float4 w1 = *(const float4*)&wb[4];
        float4 w2 = *(const float4*)&wb[8];
        float4 w3 = *(const float4*)&wb[12];
        float4 acc = *(const float4*)&cb[(size_t)lay * 512 + ch];
        #pragma unroll
        for (int k = 0; k < 4; k++) {
            if (l - 3 + k < 0) continue;
            float4 xv = *(const float4*)&XZ[(size_t)(gr - 3 + k) * 1024 + ch];
            acc.x += (&w0.x)[k] * xv.x; acc.y += (&w1.x)[k] * xv.y;
            acc.z += (&w2.x)[k] * xv.z; acc.w += (&w3.x)[k] * xv.w;
        }
        acc.x = silu_f(acc.x); acc.y = silu_f(acc.y);
        acc.z = silu_f(acc.z); acc.w = silu_f(acc.w);
        pa = acc;
        *(float4*)&XCb[(size_t)gr * 512 + ch] = acc;     // side product
        pb = bok ? *(const float4*)&Wg[(size_t)sr * Ktot + kbase + kt * 16 + sk]
                 : make_float4(0.f, 0.f, 0.f, 0.f);
    };

    float acc[4][4] = {};
    loadT(0);

    for (int kt = 0; kt < NT; kt++) {
        As[sk + 0][sr] = pa.x; As[sk + 1][sr] = pa.y;
        As[sk + 2][sr] = pa.z; As[sk + 3][sr] = pa.w;
        Bs[sk + 0][sr] = pb.x; Bs[sk + 1][sr] = pb.y;
        Bs[sk + 2][sr] = pb.z; Bs[sk + 3][sr] = pb.w;
        __syncthreads();
        if (kt + 1 < NT) loadT(kt + 1);
        #pragma unroll
        for (int kk = 0; kk < 16; kk++) {
            float4 a = *(const float4*)&As[kk][ty * 4];
            float4 b = *(const float4*)&Bs[kk][tx * 4];
            float av[4] = {a.x, a.y, a.z, a.w};
            float bv[4] = {b.x, b.y, b.z, b.w};
            #pragma unroll
            for (int i = 0; i < 4; i++)
                #pragma unroll
                for (int j = 0; j < 4; j++) acc[i][j] += av[i] * bv[j];
        }
        __syncthreads();
    }

    float* Cz = C + (size_t)blockIdx.z * partStride;
    const int col = tx * 4;
    if (col < Nout) {
        #pragma unroll
        for (int i = 0; i < 4; i++) {
            int r = row0 + ty * 4 + i;
            *(float4*)&Cz[(size_t)r * 48 + col] =
                make_float4(acc[i][0], acc[i][1], acc[i][2], acc[i][3]);
        }
    }
}

// ---------------------------------------------------------------------------
// Stage dbl chunk (summing the SKX x_proj slabs) into LDS.
// ---------------------------------------------------------------------------
__device__ __forceinline__ void stage_dbl(
    float dbl[CL][48], const float* __restrict__ Pdbl, int r0, int tid)
{
    for (int id = tid; id < CL * 48; id += 512) {
        int rr = id / 48, cc = id - rr * 48;
        size_t o = (size_t)(r0 + rr) * 48 + cc;
        float v = 0.f;
        #pragma unroll
        for (int s = 0; s < SKX; s++) v += Pdbl[(size_t)s * (RTOT * 48) + o];
        dbl[rr][cc] = v;
    }
}

// ---------------------------------------------------------------------------
// Scan phase A: per (gb,chunk,d) -> prod(dA), h_end with h0=0 (dt_proj fused).
// Plain tt loop (unroll+prefetch spilled in r12).
// ---------------------------------------------------------------------------
__global__ __launch_bounds__(512) void scanA(
    const float* __restrict__ XCb, const float* __restrict__ Pdbl,
    const float* __restrict__ A_log, const float* __restrict__ Wdt,
    const float* __restrict__ bdt,
    float* __restrict__ Aprod, float* __restrict__ Hend, int step)
{
    __shared__ float dbl[CL][48];
    int blk = blockIdx.x;           // gb*CH + c
    int c  = blk & (CH - 1);
    int gb = blk >> 6;
    int g  = gb >> 1;
    int lay = g * 2 + step;
    int d = threadIdx.x;
    int r0 = gb * L + c * CL;

    stage_dbl(dbl, Pdbl, r0, threadIdx.x);

    float wdt[16];
    const float* wrow = Wdt + ((size_t)lay * DI + d) * DR;
    #pragma unroll
    for (int k = 0; k < 16; k += 4) {
        float4 v = *(const float4*)&wrow[k];
        wdt[k] = v.x; wdt[k + 1] = v.y; wdt[k + 2] = v.z; wdt[k + 3] = v.w;
    }
    float bias = bdt[(size_t)lay * DI + d];

    float a[DS], h[DS], ap[DS];
    const float* al = A_log + ((size_t)lay * DI + d) * DS;
    #pragma unroll
    for (int s = 0; s < DS; s++) { a[s] = -__expf(al[s]); h[s] = 0.f; ap[s] = 1.f; }
    __syncthreads();

    for (int tt = 0; tt < CL; tt++) {
        float dtr = bias;
        #pragma unroll
        for (int k = 0; k < 16; k++) dtr += dbl[tt][k] * wdt[k];
        float dt = softplus_f(dtr);
        float xc = XCb[(size_t)(r0 + tt) * DI + d];
        float dx = dt * xc;
        #pragma unroll
        for (int s = 0; s < DS; s++) {
            float da = __expf(dt * a[s]);
            h[s] = da * h[s] + dx * dbl[tt][16 + s];
            ap[s] *= da;
        }
    }
    size_t base = ((size_t)(gb * DI + d) * CH + c) * DS;
    #pragma unroll
    for (int q = 0; q < 4; q++) {
        *(float4*)&Aprod[base + q * 4] = make_float4(ap[q*4], ap[q*4+1], ap[q*4+2], ap[q*4+3]);
        *(float4*)&Hend [base + q * 4] = make_float4(h[q*4],  h[q*4+1],  h[q*4+2],  h[q*4+3]);
    }
}

// ---------------------------------------------------------------------------
// Combine: serial exclusive scan over CH chunks per (gb,d,s) lane.
// ---------------------------------------------------------------------------
__global__ __launch_bounds__(256) void scanCombine(
    const float* __restrict__ Aprod, const float* __restrict__ Hend,
    float* __restrict__ Hinit)
{
    int idx = blockIdx.x * 256 + threadIdx.x;  // (gb*DI+d)*DS + s
    int s  = idx & 15;
    int gd = idx >> 4;
    size_t base = (size_t)gd * CH * DS + s;
    float h = 0.f;
    for (int c0 = 0; c0 < CH; c0 += 8) {
        float ap[8], e[8];
        #pragma unroll
        for (int j = 0; j < 8; j++) {
            size_t o = base + (size_t)(c0 + j) * DS;
            ap[j] = Aprod[o]; e[j] = Hend[o];
        }
        #pragma unroll
        for (int j = 0; j < 8; j++) {
            Hinit[base + (size_t)(c0 + j) * DS] = h;
            h = ap[j] * h + e[j];
        }
    }
}

// ---------------------------------------------------------------------------
// Scan phase B + FUSED out_proj: replay with h_init, y -> LDS (bf16 hi/lo),
// per-wave 3xbf16 MFMA epilogue with REGISTER-PRELOADED weight rows (all 32
// bh8 loads issued before the MFMA chain - one L2 latency, not 16 serial).
// OUTMODE 0: write Pout as bf16 hi/lo pairs. OUTMODE 1: scatter fp32 to d_out.
// ---------------------------------------------------------------------------
template<int OUTMODE>
__global__ __launch_bounds__(512) void scanB_fused(
    const float* __restrict__ XCb, const float* __restrict__ Pdbl,
    const float* __restrict__ XZ, const float* __restrict__ A_log,
    const float* __restrict__ Wdt, const float* __restrict__ bdt,
    const float* __restrict__ Dp, const float* __restrict__ Hinit,
    const short* __restrict__ Woh, const short* __restrict__ Wol,
    float* __restrict__ Cout, short* __restrict__ Ph, short* __restrict__ Pl,
    int step)
{
    __shared__ float dbl[CL][48];
    __shared__ short Ys_hi[CL * YSTR];
    __shared__ short Ys_lo[CL * YSTR];
    int blk = blockIdx.x;
    int c  = blk & (CH - 1);
    int gb = blk >> 6;
    int g  = gb >> 1;
    int lay = g * 2 + step;
    int d = threadIdx.x;
    int r0 = gb * L + c * CL;

    stage_dbl(dbl, Pdbl, r0, threadIdx.x);

    float xc[CL], zz[CL];
    #pragma unroll
    for (int tt = 0; tt < CL; tt++) xc[tt] = XCb[(size_t)(r0 + tt) * DI + d];
    #pragma unroll
    for (int tt = 0; tt < CL; tt++) zz[tt] = XZ[(size_t)(r0 + tt) * 1024 + 512 + d];

    float wdt[16];
    const float* wrow = Wdt + ((size_t)lay * DI + d) * DR;
    #pragma unroll
    for (int k = 0; k < 16; k += 4) {
        float4 v = *(const float4*)&wrow[k];
        wdt[k] = v.x; wdt[k + 1] = v.y; wdt[k + 2] = v.z; wdt[k + 3] = v.w;
    }
    float bias = bdt[(size_t)lay * DI + d];

    float a[DS], h[DS];
    const float* al = A_log + ((size_t)lay * DI + d) * DS;
    size_t base = ((size_t)(gb * DI + d) * CH + c) * DS;
    #pragma unroll
    for (int q = 0; q < 4; q++) {
        float4 hv = *(const float4*)&Hinit[base + q * 4];
        h[q*4] = hv.x; h[q*4+1] = hv.y; h[q*4+2] = hv.z; h[q*4+3] = hv.w;
    }
    #pragma unroll
    for (int s = 0; s < DS; s++) a[s] = -__expf(al[s]);
    float Dv = Dp[(size_t)lay * DI + d];
    __syncthreads();

    #pragma unroll
    for (int tt = 0; tt < CL; tt++) {
        float dtr = bias;
        #pragma unroll
        for (int k = 0; k < 16; k++) dtr += dbl[tt][k] * wdt[k];
        float dt = softplus_f(dtr);
        float dx = dt * xc[tt];
        float y = 0.f;
        #pragma unroll
        for (int s = 0; s < DS; s++) {
            float da = __expf(dt * a[s]);
            h[s] = da * h[s] + dx * dbl[tt][16 + s];
            y += h[s] * dbl[tt][32 + s];
        }
        y += xc[tt] * Dv;
        y *= silu_f(zz[tt]);
        unsigned short hs = f2bf(y);
        Ys_hi[tt * YSTR + d] = (short)hs;
        Ys_lo[tt * YSTR + d] = (short)f2bf(y - bf2f(hs));
    }
    __syncthreads();

    // ---- fused out_proj epilogue: 16 rows x 256 cols, K=512 ----
    const int lane = threadIdx.x & 63, wv = threadIdx.x >> 6;
    const int m = lane & 15, quad = lane >> 4;
    const size_t wbase = (size_t)lay * DM * DI;

    #pragma unroll
    for (int q = 0; q < 2; q++) {
        const int coln = wv * 32 + q * 16 + m;
        const size_t wrow2 = wbase + (size_t)coln * DI;
        // preload the whole weight row (hi+lo) into registers: 32 loads,
        // one latency, then a pure LDS+MFMA chain.
        bh8 wh[16], wl[16];
        #pragma unroll
        for (int i = 0; i < 16; i++) {
            const int kk = i * 32 + quad * 8;
            wh[i] = *(const bh8*)&Woh[wrow2 + kk];
            wl[i] = *(const bh8*)&Wol[wrow2 + kk];
        }
        f4x acc = {};
        #pragma unroll
        for (int i = 0; i < 16; i++) {
            const int kk = i * 32 + quad * 8;
            bh8 ahv = *(bh8*)&Ys_hi[m * YSTR + kk];
            bh8 alv = *(bh8*)&Ys_lo[m * YSTR + kk];
            acc = __builtin_amdgcn_mfma_f32_16x16x32_bf16(ahv, wh[i], acc, 0, 0, 0);
            acc = __builtin_amdgcn_mfma_f32_16x16x32_bf16(ahv, wl[i], acc, 0, 0, 0);
            acc = __builtin_amdgcn_mfma_f32_16x16x32_bf16(alv, wh[i], acc, 0, 0, 0);
        }
        #pragma unroll
        for (int r = 0; r < 4; r++) {
            int tt = quad * 4 + r;
            int grow = r0 + tt;
            if (OUTMODE == 0) {
                size_t o = (size_t)grow * DM + coln;
                unsigned short hs = f2bf(acc[r]);
                Ph[o] = (short)hs;
                Pl[o] = (short)f2bf(acc[r] - bf2f(hs));
            } else {
                int b = (grow >> 10) & 1, l = grow & 1023;
                size_t dst = (g == 0)
                    ? ((size_t)(b * 1024 + l) * 512 + coln)
                    : ((size_t)(b * 1024 + (1023 - l)) * 512 + 256 + coln);
                Cout[dst] = acc[r];
            }
        }
    }
}

extern "C" void kernel_launch(void* const* d_in, const int* in_sizes, int n_in,
                              void* d_out, int out_size, void* d_ws, size_t ws_size,
                              hipStream_t stream)
{
    const float* x        = (const float*)d_in[0];
    const float* in_proj  = (const float*)d_in[1];
    const float* conv_w   = (const float*)d_in[2];
    const float* conv_b   = (const float*)d_in[3];
    const float* x_proj   = (const float*)d_in[4];
    const float* dt_proj  = (const float*)d_in[5];
    const float* dt_bias  = (const float*)d_in[6];
    const float* A_log    = (const float*)d_in[7];
    const float* Dp       = (const float*)d_in[8];
    const float* out_proj = (const float*)d_in[9];
    float* out = (float*)d_out;

    float* w = (float*)d_ws;
    size_t o = 0;
    float* XZ    = w + o; o += (size_t)RTOT * 1024;
    float* XCb   = w + o; o += (size_t)RTOT * DI;
    float* Pdbl  = w + o; o += (size_t)SKX * RTOT * 48;
    float* Aprod = w + o; o += (size_t)G * BB * DI * CH * DS;
    float* Hend  = w + o; o += (size_t)G * BB * DI * CH * DS;
    float* Hinit = w + o; o += (size_t)G * BB * DI * CH * DS;
    short* Wih   = (short*)(w + o); o += NWIN / 2;
    short* Wil   = (short*)(w + o); o += NWIN / 2;
    short* Woh   = (short*)(w + o); o += NWOUT / 2;
    short* Wol   = (short*)(w + o); o += NWOUT / 2;
    short* Ph    = (short*)(w + o); o += (size_t)RTOT * DM / 2;
    short* Pl    = (short*)(w + o); o += (size_t)RTOT * DM / 2;
    (void)ws_size; (void)in_sizes; (void)n_in; (void)out_size;

    // one-time weight pre-conversion (fp32 -> bf16 hi/lo), single dispatch
    {
        int n4a = NWIN / 4, n4b = NWOUT / 4;
        cvtW2<<<(n4a + n4b + 255) / 256, 256, 0, stream>>>(
            in_proj, Wih, Wil, n4a, out_proj, Woh, Wol, n4b);
    }

    for (int step = 0; step < 2; step++) {
        // in_proj: 4096x1024, K=256, MFMA 3xbf16. 128x64 tiles -> 512 blocks.
        if (step == 0)
            mfma_inproj<1><<<dim3(16, 32), 256, 0, stream>>>(
                x, nullptr, nullptr, Wih, Wil, 0, XZ);
        else
            mfma_inproj<0><<<dim3(16, 32), 256, 0, stream>>>(
                nullptr, Ph, Pl, Wih, Wil, 1, XZ);

        // x_proj (+fused conv+silu, side-writes XCb): split-8 -> 512 blocks.
        gemm_xproj<SKX><<<dim3(1, 64, SKX), 256, 0, stream>>>(
            XZ, conv_w, conv_b, XCb, x_proj, step, Pdbl, (size_t)RTOT * 48);

        // chunked scan: A -> combine -> B(+fused out_proj); 256 blocks.
        scanA<<<G * BB * CH, 512, 0, stream>>>(
            XCb, Pdbl, A_log, dt_proj, dt_bias, Aprod, Hend, step);
        scanCombine<<<(G * BB * DI * DS) / 256, 256, 0, stream>>>(Aprod, Hend, Hinit);
        if (step == 0)
            scanB_fused<0><<<G * BB * CH, 512, 0, stream>>>(
                XCb, Pdbl, XZ, A_log, dt_proj, dt_bias, Dp, Hinit,
                Woh, Wol, nullptr, Ph, Pl, 0);
        else
            scanB_fused<1><<<G * BB * CH, 512, 0, stream>>>(
                XCb, Pdbl, XZ, A_log, dt_proj, dt_bias, Dp, Hinit,
                Woh, Wol, out, nullptr, nullptr, 1);
    }
}

// Round 15
// 242.658 us; speedup vs baseline: 1.2407x; 1.0038x over previous
//
#include <hip/hip_runtime.h>
#include <math.h>

#define G 2
#define BB 2
#define L 1024
#define DM 256
#define DI 512
#define DS 16
#define DR 16
#define CH 64              // chunks per sequence (128 doubled epilogue work - r13)
#define CL 16              // L / CH
#define RTOT (G*BB*L)      // 4096 rows per layer-step
#define SKX 8              // x_proj split-K factor
#define YSTR 520           // Ys LDS row stride (shorts); 514 doubled conflicts (r12)

#define NWIN  (4 * 2 * DI * DM)   // in_proj elements (4 layers)
#define NWOUT (4 * DM * DI)       // out_proj elements

typedef short bh8 __attribute__((ext_vector_type(8)));
typedef float f4x __attribute__((ext_vector_type(4)));

__device__ __forceinline__ float silu_f(float x) { return x / (1.f + __expf(-x)); }
// fast softplus: 2 transcendentals instead of libm log1pf expansion (r14 win)
__device__ __forceinline__ float softplus_f(float x) {
    return (x > 20.f) ? x : __logf(1.f + __expf(x));
}

__device__ __forceinline__ unsigned short f2bf(float f) {
    unsigned u = __float_as_uint(f);
    unsigned r = u + 0x7FFFu + ((u >> 16) & 1u);
    return (unsigned short)(r >> 16);
}
__device__ __forceinline__ float bf2f(unsigned short s) {
    return __uint_as_float(((unsigned)s) << 16);
}

// ---------------------------------------------------------------------------
// One-time weight pre-conversion (both weight arrays in ONE dispatch):
// fp32 -> (bf16 hi, bf16 lo) pairs.
// ---------------------------------------------------------------------------
__global__ __launch_bounds__(256) void cvtW2(
    const float* __restrict__ Wa, short* __restrict__ Wah, short* __restrict__ Wal, int n4a,
    const float* __restrict__ Wb, short* __restrict__ Wbh, short* __restrict__ Wbl, int n4b)
{
    int i = blockIdx.x * 256 + threadIdx.x;
    const float* W; short *Wh, *Wl;
    if (i < n4a) { W = Wa; Wh = Wah; Wl = Wal; }
    else if (i < n4a + n4b) { i -= n4a; W = Wb; Wh = Wbh; Wl = Wbl; }
    else return;
    float4 v = *(const float4*)&W[(size_t)i * 4];
    short4 h, l;
    unsigned short s;
    s = f2bf(v.x); h.x = (short)s; l.x = (short)f2bf(v.x - bf2f(s));
    s = f2bf(v.y); h.y = (short)s; l.y = (short)f2bf(v.y - bf2f(s));
    s = f2bf(v.z); h.z = (short)s; l.z = (short)f2bf(v.z - bf2f(s));
    s = f2bf(v.w); h.w = (short)s; l.w = (short)f2bf(v.w - bf2f(s));
    *(short4*)&Wh[(size_t)i * 4] = h;
    *(short4*)&Wl[(size_t)i * 4] = l;
}

// ---------------------------------------------------------------------------
// in_proj MFMA GEMM (3xbf16). BM=128, N=1024, K=256.
// AMAP 1: A = x (fp32) with g-dependent time reversal (step 0).
// AMAP 0: A = Pout as pre-split bf16 hi/lo (step 1) - cvt-free staging.
// ---------------------------------------------------------------------------
template<int AMAP>
__global__ __launch_bounds__(256) void mfma_inproj(
    const float* __restrict__ Ax,
    const short* __restrict__ Ah, const short* __restrict__ Al,
    const short* __restrict__ Wh, const short* __restrict__ Wl,
    int step, float* __restrict__ C)
{
    constexpr int BM = 128, Ktot = DM, Nout = 2 * DI, ldc = 1024;
    __shared__ short As_hi[BM * 40];
    __shared__ short As_lo[BM * 40];
    __shared__ short Bs_hi[64 * 40];
    __shared__ short Bs_lo[64 * 40];

    const int row0 = blockIdx.y * BM;
    const int col0 = blockIdx.x * 64;
    const int g    = row0 >> 11;
    const int lay  = g * 2 + step;
    const short* Whg = Wh + (size_t)lay * Nout * Ktot;
    const short* Wlg = Wl + (size_t)lay * Nout * Ktot;
    const int t    = threadIdx.x;
    const int lane = t & 63, wv = t >> 6;
    const int m = lane & 15, quad = lane >> 4;
    const int wr = wv >> 1, wc = wv & 1;
    const int NT = Ktot / 32;     // 8

    float4 pa[4];
    short4 pah[4], pal[4], pbh[2], pbl[2];
    auto loadT = [&](int kt) {
        const int kb = kt * 32;
        #pragma unroll
        for (int i = 0; i < 4; i++) {
            int id = t + 256 * i;
            int row = id >> 3, kq = id & 7;
            if (AMAP == 1) {
                int gr = row0 + row;
                int gg = gr >> 11, b = (gr >> 10) & 1, l = gr & 1023;
                int sl = gg ? (1023 - l) : l;
                pa[i] = *(const float4*)&Ax[(size_t)(b * 1024 + sl) * Ktot + kb + kq * 4];
            } else {
                size_t o = (size_t)(row0 + row) * Ktot + kb + kq * 4;
                pah[i] = *(const short4*)&Ah[o];
                pal[i] = *(const short4*)&Al[o];
            }
        }
        #pragma unroll
        for (int i = 0; i < 2; i++) {
            int id = t + 256 * i;
            int row = id >> 3, kq = id & 7;
            size_t o = (size_t)(col0 + row) * Ktot + kb + kq * 4;
            pbh[i] = *(const short4*)&Whg[o];
            pbl[i] = *(const short4*)&Wlg[o];
        }
    };

    f4x acc[4][2] = {};
    loadT(0);

    for (int kt = 0; kt < NT; kt++) {
        #pragma unroll
        for (int i = 0; i < 4; i++) {
            int id = t + 256 * i;
            int row = id >> 3, kq = id & 7;
            if (AMAP == 1) {
                float4 v = pa[i];
                short4 h, l;
                unsigned short s;
                s = f2bf(v.x); h.x = (short)s; l.x = (short)f2bf(v.x - bf2f(s));
                s = f2bf(v.y); h.y = (short)s; l.y = (short)f2bf(v.y - bf2f(s));
                s = f2bf(v.z); h.z = (short)s; l.z = (short)f2bf(v.z - bf2f(s));
                s = f2bf(v.w); h.w = (short)s; l.w = (short)f2bf(v.w - bf2f(s));
                *(short4*)&As_hi[row * 40 + kq * 4] = h;
                *(short4*)&As_lo[row * 40 + kq * 4] = l;
            } else {
                *(short4*)&As_hi[row * 40 + kq * 4] = pah[i];
                *(short4*)&As_lo[row * 40 + kq * 4] = pal[i];
            }
        }
        #pragma unroll
        for (int i = 0; i < 2; i++) {
            int id = t + 256 * i;
            int row = id >> 3, kq = id & 7;
            *(short4*)&Bs_hi[row * 40 + kq * 4] = pbh[i];
            *(short4*)&Bs_lo[row * 40 + kq * 4] = pbl[i];
        }
        __syncthreads();
        if (kt + 1 < NT) loadT(kt + 1);

        bh8 ah[4], al[4], bh[2], bl[2];
        #pragma unroll
        for (int p = 0; p < 4; p++) {
            int r = wr * 64 + p * 16 + m;
            ah[p] = *(bh8*)&As_hi[r * 40 + quad * 8];
            al[p] = *(bh8*)&As_lo[r * 40 + quad * 8];
        }
        #pragma unroll
        for (int q = 0; q < 2; q++) {
            int r = wc * 32 + q * 16 + m;
            bh[q] = *(bh8*)&Bs_hi[r * 40 + quad * 8];
            bl[q] = *(bh8*)&Bs_lo[r * 40 + quad * 8];
        }
        #pragma unroll
        for (int p = 0; p < 4; p++)
            #pragma unroll
            for (int q = 0; q < 2; q++) {
                acc[p][q] = __builtin_amdgcn_mfma_f32_16x16x32_bf16(ah[p], bh[q], acc[p][q], 0, 0, 0);
                acc[p][q] = __builtin_amdgcn_mfma_f32_16x16x32_bf16(ah[p], bl[q], acc[p][q], 0, 0, 0);
                acc[p][q] = __builtin_amdgcn_mfma_f32_16x16x32_bf16(al[p], bh[q], acc[p][q], 0, 0, 0);
            }
        __syncthreads();
    }

    #pragma unroll
    for (int p = 0; p < 4; p++)
        #pragma unroll
        for (int q = 0; q < 2; q++) {
            int gcol = col0 + wc * 32 + q * 16 + m;
            #pragma unroll
            for (int r = 0; r < 4; r++) {
                int grow = row0 + wr * 64 + p * 16 + quad * 4 + r;
                C[(size_t)grow * ldc + gcol] = acc[p][q][r];
            }
        }
}

// ---------------------------------------------------------------------------
// x_proj GEMM (fp32) with the depthwise conv+silu FUSED into the A-staging.
// ---------------------------------------------------------------------------
template<int SPLITK>
__global__ __launch_bounds__(256) void gemm_xproj(
    const float* __restrict__ XZ, const float* __restrict__ cw,
    const float* __restrict__ cb, float* __restrict__ XCb,
    const float* __restrict__ W, int step,
    float* __restrict__ C, size_t partStride)
{
    constexpr int Nout = 48, Ktot = DI;
    __shared__ float As[16][68];
    __shared__ float Bs[16][68];

    const int row0 = blockIdx.y * 64;
    const int g    = row0 >> 11;
    const int lay  = g * 2 + step;
    const float* Wg = W + (size_t)lay * Nout * Ktot;
    const int t  = threadIdx.x;
    const int tx = t & 15, ty = t >> 4;
    const int Kc    = Ktot / SPLITK;
    const int kbase = blockIdx.z * Kc;
    const int NT    = Kc / 16;

    const int sr = t >> 2;
    const int sk = (t & 3) * 4;
    const int gr = row0 + sr;
    const int l  = gr & 1023;
    const bool bok = (sr < Nout);

    float4 pa, pb;
    auto loadT = [&](int kt) {
        const int ch = kbase + kt * 16 + sk;
        const float* wb = cw + ((size_t)lay * 512 + ch) * 4;
        float4 w0 = *(const float4*)&wb[0];
        float4 w1 = *(const float4*)&wb[4];
        float4 w2 = *(const float4*)&wb[8];
        float4 w3 = *(const float4*)&wb[12];
        float4 acc = *(const float4*)&cb[(size_t)lay * 512 + ch];
        #pragma unroll
        for (int k = 0; k < 4; k++) {
            if (l - 3 + k < 0) continue;
            float4 xv = *(const float4*)&XZ[(size_t)(gr - 3 + k) * 1024 + ch];
            acc.x += (&w0.x)[k] * xv.x; acc.y += (&w1.x)[k] * xv.y;
            acc.z += (&w2.x)[k] * xv.z; acc.w += (&w3.x)[k] * xv.w;
        }
        acc.x = silu_f(acc.x); acc.y = silu_f(acc.y);
        acc.z = silu_f(acc.z); acc.w = silu_f(acc.w);
        pa = acc;
        *(float4*)&XCb[(size_t)gr * 512 + ch] = acc;     // side product
        pb = bok ? *(const float4*)&Wg[(size_t)sr * Ktot + kbase + kt * 16 + sk]
                 : make_float4(0.f, 0.f, 0.f, 0.f);
    };

    float acc[4][4] = {};
    loadT(0);

    for (int kt = 0; kt < NT; kt++) {
        As[sk + 0][sr] = pa.x; As[sk + 1][sr] = pa.y;
        As[sk + 2][sr] = pa.z; As[sk + 3][sr] = pa.w;
        Bs[sk + 0][sr] = pb.x; Bs[sk + 1][sr] = pb.y;
        Bs[sk + 2][sr] = pb.z; Bs[sk + 3][sr] = pb.w;
        __syncthreads();
        if (kt + 1 < NT) loadT(kt + 1);
        #pragma unroll
        for (int kk = 0; kk < 16; kk++) {
            float4 a = *(const float4*)&As[kk][ty * 4];
            float4 b = *(const float4*)&Bs[kk][tx * 4];
            float av[4] = {a.x, a.y, a.z, a.w};
            float bv[4] = {b.x, b.y, b.z, b.w};
            #pragma unroll
            for (int i = 0; i < 4; i++)
                #pragma unroll
                for (int j = 0; j < 4; j++) acc[i][j] += av[i] * bv[j];
        }
        __syncthreads();
    }

    float* Cz = C + (size_t)blockIdx.z * partStride;
    const int col = tx * 4;
    if (col < Nout) {
        #pragma unroll
        for (int i = 0; i < 4; i++) {
            int r = row0 + ty * 4 + i;
            *(float4*)&Cz[(size_t)r * 48 + col] =
                make_float4(acc[i][0], acc[i][1], acc[i][2], acc[i][3]);
        }
    }
}

// ---------------------------------------------------------------------------
// Scan phase A: sums the SKX slabs into LDS *and* side-writes compact DBLc
// (scanB then reads 0.79MB instead of re-summing 6.3MB). dt_proj fused.
// xc: depth-1 software pipeline (scalar, spill-safe; r12's array form spilled).
// ---------------------------------------------------------------------------
__global__ __launch_bounds__(512) void scanA(
    const float* __restrict__ XCb, const float* __restrict__ Pdbl,
    const float* __restrict__ A_log, const float* __restrict__ Wdt,
    const float* __restrict__ bdt, float* __restrict__ DBLc,
    float* __restrict__ Aprod, float* __restrict__ Hend, int step)
{
    __shared__ float dbl[CL][48];
    int blk = blockIdx.x;           // gb*CH + c
    int c  = blk & (CH - 1);
    int gb = blk >> 6;
    int g  = gb >> 1;
    int lay = g * 2 + step;
    int d = threadIdx.x;
    int r0 = gb * L + c * CL;

    for (int id = threadIdx.x; id < CL * 48; id += 512) {
        int rr = id / 48, cc = id - rr * 48;
        size_t o = (size_t)(r0 + rr) * 48 + cc;
        float v = 0.f;
        #pragma unroll
        for (int s = 0; s < SKX; s++) v += Pdbl[(size_t)s * (RTOT * 48) + o];
        dbl[rr][cc] = v;
        DBLc[o] = v;                 // compact side-write for scanB
    }

    float wdt[16];
    const float* wrow = Wdt + ((size_t)lay * DI + d) * DR;
    #pragma unroll
    for (int k = 0; k < 16; k += 4) {
        float4 v = *(const float4*)&wrow[k];
        wdt[k] = v.x; wdt[k + 1] = v.y; wdt[k + 2] = v.z; wdt[k + 3] = v.w;
    }
    float bias = bdt[(size_t)lay * DI + d];

    float a[DS], h[DS], ap[DS];
    const float* al = A_log + ((size_t)lay * DI + d) * DS;
    #pragma unroll
    for (int s = 0; s < DS; s++) { a[s] = -__expf(al[s]); h[s] = 0.f; ap[s] = 1.f; }
    float xc_next = XCb[(size_t)r0 * DI + d];
    __syncthreads();

    for (int tt = 0; tt < CL; tt++) {
        float xcv = xc_next;
        if (tt + 1 < CL) xc_next = XCb[(size_t)(r0 + tt + 1) * DI + d];
        float dtr = bias;
        #pragma unroll
        for (int k = 0; k < 16; k++) dtr += dbl[tt][k] * wdt[k];
        float dt = softplus_f(dtr);
        float dx = dt * xcv;
        #pragma unroll
        for (int s = 0; s < DS; s++) {
            float da = __expf(dt * a[s]);
            h[s] = da * h[s] + dx * dbl[tt][16 + s];
            ap[s] *= da;
        }
    }
    size_t base = ((size_t)(gb * DI + d) * CH + c) * DS;
    #pragma unroll
    for (int q = 0; q < 4; q++) {
        *(float4*)&Aprod[base + q * 4] = make_float4(ap[q*4], ap[q*4+1], ap[q*4+2], ap[q*4+3]);
        *(float4*)&Hend [base + q * 4] = make_float4(h[q*4],  h[q*4+1],  h[q*4+2],  h[q*4+3]);
    }
}

// ---------------------------------------------------------------------------
// Combine: serial exclusive scan over CH chunks per (gb,d,s) lane.
// ---------------------------------------------------------------------------
__global__ __launch_bounds__(256) void scanCombine(
    const float* __restrict__ Aprod, const float* __restrict__ Hend,
    float* __restrict__ Hinit)
{
    int idx = blockIdx.x * 256 + threadIdx.x;  // (gb*DI+d)*DS + s
    int s  = idx & 15;
    int gd = idx >> 4;
    size_t base = (size_t)gd * CH * DS + s;
    float h = 0.f;
    for (int c0 = 0; c0 < CH; c0 += 8) {
        float ap[8], e[8];
        #pragma unroll
        for (int j = 0; j < 8; j++) {
            size_t o = base + (size_t)(c0 + j) * DS;
            ap[j] = Aprod[o]; e[j] = Hend[o];
        }
        #pragma unroll
        for (int j = 0; j < 8; j++) {
            Hinit[base + (size_t)(c0 + j) * DS] = h;
            h = ap[j] * h + e[j];
        }
    }
}

// ---------------------------------------------------------------------------
// Scan phase B + FUSED out_proj: dbl from compact DBLc (no slab re-sum);
// replay with h_init, y -> LDS (bf16 hi/lo), per-wave 3xbf16 MFMA epilogue
// with register-preloaded weight rows.
// OUTMODE 0: write Pout as bf16 hi/lo pairs. OUTMODE 1: scatter fp32 to d_out.
// ---------------------------------------------------------------------------
template<int OUTMODE>
__global__ __launch_bounds__(512) void scanB_fused(
    const float* __restrict__ XCb, const float* __restrict__ DBLc,
    const float* __restrict__ XZ, const float* __restrict__ A_log,
    const float* __restrict__ Wdt, const float* __restrict__ bdt,
    const float* __restrict__ Dp, const float* __restrict__ Hinit,
    const short* __restrict__ Woh, const short* __restrict__ Wol,
    float* __restrict__ Cout, short* __restrict__ Ph, short* __restrict__ Pl,
    int step)
{
    __shared__ float dbl[CL][48];
    __shared__ short Ys_hi[CL * YSTR];
    __shared__ short Ys_lo[CL * YSTR];
    int blk = blockIdx.x;
    int c  = blk & (CH - 1);
    int gb = blk >> 6;
    int g  = gb >> 1;
    int lay = g * 2 + step;
    int d = threadIdx.x;
    int r0 = gb * L + c * CL;

    for (int id = threadIdx.x; id < CL * 48; id += 512) {
        int rr = id / 48, cc = id - rr * 48;
        dbl[rr][cc] = DBLc[(size_t)(r0 + rr) * 48 + cc];
    }

    float xc[CL], zz[CL];
    #pragma unroll
    for (int tt = 0; tt < CL; tt++) xc[tt] = XCb[(size_t)(r0 + tt) * DI + d];
    #pragma unroll
    for (int tt = 0; tt < CL; tt++) zz[tt] = XZ[(size_t)(r0 + tt) * 1024 + 512 + d];

    float wdt[16];
    const float* wrow = Wdt + ((size_t)lay * DI + d) * DR;
    #pragma unroll
    for (int k = 0; k < 16; k += 4) {
        float4 v = *(const float4*)&wrow[k];
        wdt[k] = v.x; wdt[k + 1] = v.y; wdt[k + 2] = v.z; wdt[k + 3] = v.w;
    }
    float bias = bdt[(size_t)lay * DI + d];

    float a[DS], h[DS];
    const float* al = A_log + ((size_t)lay * DI + d) * DS;
    size_t base = ((size_t)(gb * DI + d) * CH + c) * DS;
    #pragma unroll
    for (int q = 0; q < 4; q++) {
        float4 hv = *(const float4*)&Hinit[base + q * 4];
        h[q*4] = hv.x; h[q*4+1] = hv.y; h[q*4+2] = hv.z; h[q*4+3] = hv.w;
    }
    #pragma unroll
    for (int s = 0; s < DS; s++) a[s] = -__expf(al[s]);
    float Dv = Dp[(size_t)lay * DI + d];
    __syncthreads();

    #pragma unroll
    for (int tt = 0; tt < CL; tt++) {
        float dtr = bias;
        #pragma unroll
        for (int k = 0; k < 16; k++) dtr += dbl[tt][k] * wdt[k];
        float dt = softplus_f(dtr);
        float dx = dt * xc[tt];
        float y = 0.f;
        #pragma unroll
        for (int s = 0; s < DS; s++) {
            float da = __expf(dt * a[s]);
            h[s] = da * h[s] + dx * dbl[tt][16 + s];
            y += h[s] * dbl[tt][32 + s];
        }
        y += xc[tt] * Dv;
        y *= silu_f(zz[tt]);
        unsigned short hs = f2bf(y);
        Ys_hi[tt * YSTR + d] = (short)hs;
        Ys_lo[tt * YSTR + d] = (short)f2bf(y - bf2f(hs));
    }
    __syncthreads();

    // ---- fused out_proj epilogue: 16 rows x 256 cols, K=512 ----
    const int lane = threadIdx.x & 63, wv = threadIdx.x >> 6;
    const int m = lane & 15, quad = lane >> 4;
    const size_t wbase = (size_t)lay * DM * DI;

    #pragma unroll
    for (int q = 0; q < 2; q++) {
        const int coln = wv * 32 + q * 16 + m;
        const size_t wrow2 = wbase + (size_t)coln * DI;
        bh8 wh[16], wl[16];
        #pragma unroll
        for (int i = 0; i < 16; i++) {
            const int kk = i * 32 + quad * 8;
            wh[i] = *(const bh8*)&Woh[wrow2 + kk];
            wl[i] = *(const bh8*)&Wol[wrow2 + kk];
        }
        f4x acc = {};
        #pragma unroll
        for (int i = 0; i < 16; i++) {
            const int kk = i * 32 + quad * 8;
            bh8 ahv = *(bh8*)&Ys_hi[m * YSTR + kk];
            bh8 alv = *(bh8*)&Ys_lo[m * YSTR + kk];
            acc = __builtin_amdgcn_mfma_f32_16x16x32_bf16(ahv, wh[i], acc, 0, 0, 0);
            acc = __builtin_amdgcn_mfma_f32_16x16x32_bf16(ahv, wl[i], acc, 0, 0, 0);
            acc = __builtin_amdgcn_mfma_f32_16x16x32_bf16(alv, wh[i], acc, 0, 0, 0);
        }
        #pragma unroll
        for (int r = 0; r < 4; r++) {
            int tt = quad * 4 + r;
            int grow = r0 + tt;
            if (OUTMODE == 0) {
                size_t o = (size_t)grow * DM + coln;
                unsigned short hs = f2bf(acc[r]);
                Ph[o] = (short)hs;
                Pl[o] = (short)f2bf(acc[r] - bf2f(hs));
            } else {
                int b = (grow >> 10) & 1, l = grow & 1023;
                size_t dst = (g == 0)
                    ? ((size_t)(b * 1024 + l) * 512 + coln)
                    : ((size_t)(b * 1024 + (1023 - l)) * 512 + 256 + coln);
                Cout[dst] = acc[r];
            }
        }
    }
}

extern "C" void kernel_launch(void* const* d_in, const int* in_sizes, int n_in,
                              void* d_out, int out_size, void* d_ws, size_t ws_size,
                              hipStream_t stream)
{
    const float* x        = (const float*)d_in[0];
    const float* in_proj  = (const float*)d_in[1];
    const float* conv_w   = (const float*)d_in[2];
    const float* conv_b   = (const float*)d_in[3];
    const float* x_proj   = (const float*)d_in[4];
    const float* dt_proj  = (const float*)d_in[5];
    const float* dt_bias  = (const float*)d_in[6];
    const float* A_log    = (const float*)d_in[7];
    const float* Dp       = (const float*)d_in[8];
    const float* out_proj = (const float*)d_in[9];
    float* out = (float*)d_out;

    float* w = (float*)d_ws;
    size_t o = 0;
    float* XZ    = w + o; o += (size_t)RTOT * 1024;
    float* XCb   = w + o; o += (size_t)RTOT * DI;
    float* Pdbl  = w + o; o += (size_t)SKX * RTOT * 48;
    float* DBLc  = w + o; o += (size_t)RTOT * 48;
    float* Aprod = w + o; o += (size_t)G * BB * DI * CH * DS;
    float* Hend  = w + o; o += (size_t)G * BB * DI * CH * DS;
    float* Hinit = w + o; o += (size_t)G * BB * DI * CH * DS;
    short* Wih   = (short*)(w + o); o += NWIN / 2;
    short* Wil   = (short*)(w + o); o += NWIN / 2;
    short* Woh   = (short*)(w + o); o += NWOUT / 2;
    short* Wol   = (short*)(w + o); o += NWOUT / 2;
    short* Ph    = (short*)(w + o); o += (size_t)RTOT * DM / 2;
    short* Pl    = (short*)(w + o); o += (size_t)RTOT * DM / 2;
    (void)ws_size; (void)in_sizes; (void)n_in; (void)out_size;

    // one-time weight pre-conversion (fp32 -> bf16 hi/lo), single dispatch
    {
        int n4a = NWIN / 4, n4b = NWOUT / 4;
        cvtW2<<<(n4a + n4b + 255) / 256, 256, 0, stream>>>(
            in_proj, Wih, Wil, n4a, out_proj, Woh, Wol, n4b);
    }

    for (int step = 0; step < 2; step++) {
        // in_proj: 4096x1024, K=256, MFMA 3xbf16. 128x64 tiles -> 512 blocks.
        if (step == 0)
            mfma_inproj<1><<<dim3(16, 32), 256, 0, stream>>>(
                x, nullptr, nullptr, Wih, Wil, 0, XZ);
        else
            mfma_inproj<0><<<dim3(16, 32), 256, 0, stream>>>(
                nullptr, Ph, Pl, Wih, Wil, 1, XZ);

        // x_proj (+fused conv+silu, side-writes XCb): split-8 -> 512 blocks.
        gemm_xproj<SKX><<<dim3(1, 64, SKX), 256, 0, stream>>>(
            XZ, conv_w, conv_b, XCb, x_proj, step, Pdbl, (size_t)RTOT * 48);

        // chunked scan: A(+DBLc) -> combine -> B(+fused out_proj); 256 blocks.
        scanA<<<G * BB * CH, 512, 0, stream>>>(
            XCb, Pdbl, A_log, dt_proj, dt_bias, DBLc, Aprod, Hend, step);
        scanCombine<<<(G * BB * DI * DS) / 256, 256, 0, stream>>>(Aprod, Hend, Hinit);
        if (step == 0)
            scanB_fused<0><<<G * BB * CH, 512, 0, stream>>>(
                XCb, DBLc, XZ, A_log, dt_proj, dt_bias, Dp, Hinit,
                Woh, Wol, nullptr, Ph, Pl, 0);
        else
            scanB_fused<1><<<G * BB * CH, 512, 0, stream>>>(
                XCb, DBLc, XZ, A_log, dt_proj, dt_bias, Dp, Hinit,
                Woh, Wol, out, nullptr, nullptr, 1);
    }
}